// Round 17
// baseline (389.623 us; speedup 1.0000x reference)
//
#include <hip/hip_runtime.h>
#include <cstddef>
#include <cstdint>

#define LQ 1024
#define DMQ 768
#define DSQ 256
#define DIQ 512
#define CCH 16
#define CT (LQ / CCH)

typedef unsigned short ushortT;
using f32x4 = __attribute__((ext_vector_type(4))) float;
using f32x2 = __attribute__((ext_vector_type(2))) float;
using bf16x8 = __attribute__((ext_vector_type(8))) short;
using u16x8 = __attribute__((ext_vector_type(8))) unsigned short;

__device__ __forceinline__ float sigf(float x) { return 1.f / (1.f + __expf(-x)); }
__device__ __forceinline__ float softplusf(float x) {
    return fmaxf(x, 0.f) + __logf(1.f + __expf(-fabsf(x)));
}
__device__ __forceinline__ ushortT f2bf(float f) {
    unsigned u = __float_as_uint(f);
    u += 0x7FFFu + ((u >> 16) & 1u);
    return (ushortT)(u >> 16);
}
__device__ __forceinline__ float bf2f(ushortT u) {
    return __uint_as_float(((unsigned)u) << 16);
}
__device__ __forceinline__ void gload_lds16(const void* g, void* l) {
    __builtin_amdgcn_global_load_lds((const __attribute__((address_space(1))) void*)g,
                                     (__attribute__((address_space(3))) void*)l, 16, 0, 0);
}

// ---------------- lengths ----------------
__global__ void k_lengths(const int* __restrict__ mask, int* __restrict__ lengths) {
    int b = blockIdx.x;
    int s = 0;
    for (int t = threadIdx.x; t < LQ; t += 256) s += mask[b * LQ + t];
    __shared__ int sm[256];
    sm[threadIdx.x] = s;
    __syncthreads();
    for (int o = 128; o > 0; o >>= 1) {
        if (threadIdx.x < o) sm[threadIdx.x] += sm[threadIdx.x + o];
        __syncthreads();
    }
    if (threadIdx.x == 0) lengths[b] = sm[0];
}

// ---------------- merged weight conversion ----------------
__global__ void k_prep(const float* __restrict__ ipw, const float* __restrict__ fusw,
                       const float* __restrict__ xpw, ushortT* __restrict__ ipwb,
                       ushortT* __restrict__ fuswb, ushortT* __restrict__ xpwb) {
    int i = blockIdx.x * 256 + threadIdx.x;
    if (i < 1572864) { ipwb[i] = f2bf(ipw[i]); return; }
    i -= 1572864;
    if (i < 589824) { fuswb[i] = f2bf(fusw[i]); return; }
    i -= 589824;
    if (i >= 393216) return;
    int inst = i >> 16, rem = i & 65535;
    int row = rem >> 9, col = rem & 511;
    float v = (row < 48) ? xpw[((size_t)inst * 48 + row) * 512 + col] : 0.f;
    xpwb[i] = f2bf(v);
}

// -------- fused weight, dir-interleaved: wf2[i][m][dir*512+d] --------
__global__ void k_wfuse(const float* __restrict__ opw, const float* __restrict__ mow,
                        ushortT* __restrict__ wf) {
    int idx = blockIdx.x * 256 + threadIdx.x;  // 196608 = 6*256*128
    int inst = idx >> 15;
    int rem = idx & 32767;
    int m = rem >> 7;
    int d0 = (rem & 127) * 4;
    int i = inst >> 1, dir = inst & 1;
    const float* a = opw + (size_t)i * 131072 + dir * 256 + (size_t)m * 512;
    const float* bm = mow + (size_t)inst * 131072 + d0;
    float s0 = 0.f, s1 = 0.f, s2 = 0.f, s3 = 0.f;
    for (int c = 0; c < 256; c++) {
        float av = a[c];
        float4 bv = *(const float4*)(bm + (size_t)c * 512);
        s0 = fmaf(av, bv.x, s0);
        s1 = fmaf(av, bv.y, s1);
        s2 = fmaf(av, bv.z, s2);
        s3 = fmaf(av, bv.w, s3);
    }
    ushort4 r = {f2bf(s0), f2bf(s1), f2bf(s2), f2bf(s3)};
    *(ushort4*)(wf + ((size_t)i * 256 + m) * 1024 + dir * 512 + d0) = r;
}

// -------- per-batch att-scaled fus weight --------
__global__ void k_fusw8(const float* __restrict__ fusw, const float* __restrict__ att,
                        ushortT* __restrict__ wf8) {
    int idx = blockIdx.x * 256 + threadIdx.x;  // 8*768*192
    int b = idx / 147456;
    int rem = idx % 147456;
    int n = rem / 192;
    int k0 = (rem % 192) * 4;
    float4 w = *(const float4*)(fusw + (size_t)n * 768 + k0);
    float4 a = *(const float4*)(att + (size_t)b * 768 + k0);
    ushort4 r = {f2bf(w.x * a.x), f2bf(w.y * a.y), f2bf(w.z * a.z), f2bf(w.w * a.w)};
    *(ushort4*)(wf8 + ((size_t)(b * 768 + n)) * 768 + k0) = r;
}

// ------- dilated dw conv + BN + GELU -> c bf16 (all 3 scales, float4/thread) -------
__global__ __launch_bounds__(64) void k_pool(const float* __restrict__ hid,
                                             const float* __restrict__ pw,
                                             const float* __restrict__ pb,
                                             const float* __restrict__ bg,
                                             const float* __restrict__ bb,
                                             const float* __restrict__ brm,
                                             const float* __restrict__ brv,
                                             ushortT* __restrict__ cdst) {
    int gidx = blockIdx.x;  // 3*8192
    int isc = gidx >> 13;
    int idx = gidx & 8191;
    int l = idx & (LQ - 1);
    int b = idx >> 10;
    int ch0 = threadIdx.x * 4;
    int dil = 1 << isc;
    int wci0 = isc * DSQ + ch0;
    const float* xb = hid + (size_t)b * LQ * DMQ + isc * DSQ + ch0;
    float wv[12];
    *(float4*)&wv[0] = *(const float4*)(pw + (size_t)wci0 * 3);
    *(float4*)&wv[4] = *(const float4*)(pw + (size_t)wci0 * 3 + 4);
    *(float4*)&wv[8] = *(const float4*)(pw + (size_t)wci0 * 3 + 8);
    float pbv[4], bgv[4], bbv[4], rmv[4], rvv[4];
    *(float4*)pbv = *(const float4*)(pb + wci0);
    *(float4*)bgv = *(const float4*)(bg + wci0);
    *(float4*)bbv = *(const float4*)(bb + wci0);
    *(float4*)rmv = *(const float4*)(brm + wci0);
    *(float4*)rvv = *(const float4*)(brv + wci0);
    float xm[4] = {0.f, 0.f, 0.f, 0.f}, xc[4], xp[4] = {0.f, 0.f, 0.f, 0.f};
    int lm = l - dil, lp = l + dil;
    if (lm >= 0) *(float4*)xm = *(const float4*)(xb + (size_t)lm * DMQ);
    *(float4*)xc = *(const float4*)(xb + (size_t)l * DMQ);
    if (lp < LQ) *(float4*)xp = *(const float4*)(xb + (size_t)lp * DMQ);
    ushort4 o;
#pragma unroll
    for (int j = 0; j < 4; j++) {
        float acc = pbv[j];
        acc = fmaf(wv[j * 3 + 0], xm[j], acc);
        acc = fmaf(wv[j * 3 + 1], xc[j], acc);
        acc = fmaf(wv[j * 3 + 2], xp[j], acc);
        float xn = (acc - rmv[j]) * rsqrtf(rvv[j] + 1e-5f) * bgv[j] + bbv[j];
        float y = 0.5f * xn * (1.0f + erff(xn * 0.70710678118654752f));
        ((ushortT*)&o)[j] = f2bf(y);
    }
    *(ushort4*)(cdst + (size_t)isc * 2097152 + (size_t)idx * DSQ + ch0) = o;
}

// ---------------- batched bf16 GEMM: dbuf pipeline + LDS-transpose bf16 epilogue -------
template <int FLIPA, int FLIPC, int BIAS, int ACC, int CBF16, int GATE>
__global__ __launch_bounds__(256) void gemm_bf16(
    const ushortT* __restrict__ A, const ushortT* __restrict__ Bw, void* __restrict__ Cv,
    const float* __restrict__ bias, const ushortT* __restrict__ Yb,
    const int* __restrict__ lengths, int N, int Kd, int lda, int ldc, int ldy, long sAz,
    int zshiftA, long sBz, long sCz, long sCzOdd, int zshiftC, long sYz, int sBiasz) {
    __shared__ ushortT Als[2][8192];
    __shared__ ushortT Bls[2][8192];
    const int z = blockIdx.z;
    A += (size_t)(z >> zshiftA) * sAz;
    Bw += (size_t)z * sBz;
    size_t cbase = (size_t)(z >> zshiftC) * sCz +
                   (size_t)(z & ((1 << zshiftC) - 1)) * sCzOdd;
    float* Cf = (float*)Cv + (CBF16 ? 0 : cbase);
    ushortT* Cb = (ushortT*)Cv + (CBF16 ? cbase : 0);
    if (BIAS) bias += (size_t)z * sBiasz;
    if (GATE) Yb += (size_t)z * sYz;

    const int tid = threadIdx.x;
    const int lane = tid & 63;
    const int wave = tid >> 6;
    const int wr = wave >> 1, wc = wave & 1;
    const int row0 = blockIdx.y * 128, col0 = blockIdx.x * 128;
    const bool doflipA = (FLIPA == 1) || (FLIPA == 2 && (z & 1));
    const bool doflipC = (FLIPC == 1) || (FLIPC == 2 && (z & 1));
    int len = 0;
    if (FLIPA || FLIPC) len = lengths[row0 >> 10];

    const int srow = wave * 8 + (lane >> 3);  // + it*32
    const int scol = (lane & 7) * 8;

    auto stage = [&](int buf, int k0) {
#pragma unroll
        for (int it = 0; it < 4; it++) {
            int row = it * 32 + srow;
            int grow = row0 + row;
            if (FLIPA) {
                if (doflipA) {
                    int t = grow & (LQ - 1);
                    int ts = (t < len) ? (len - 1 - t) : t;
                    grow = (grow & ~(LQ - 1)) | ts;
                }
            }
            gload_lds16(A + (size_t)grow * lda + k0 + scol,
                        &Als[buf][it * 2048 + wave * 512]);
        }
#pragma unroll
        for (int it = 0; it < 4; it++) {
            int row = it * 32 + srow;
            gload_lds16(Bw + (size_t)(col0 + row) * Kd + k0 + scol,
                        &Bls[buf][it * 2048 + wave * 512]);
        }
    };

    f32x4 acc[4][4];
#pragma unroll
    for (int i = 0; i < 4; i++)
#pragma unroll
        for (int j = 0; j < 4; j++) acc[i][j] = (f32x4){0.f, 0.f, 0.f, 0.f};

    const int niter = Kd >> 6;
    stage(0, 0);
    for (int it = 0; it < niter; ++it) {
        const int cur = it & 1;
        if (it + 1 < niter) {
            stage(cur ^ 1, (it + 1) << 6);
            asm volatile("s_waitcnt vmcnt(8)" ::: "memory");
        } else {
            asm volatile("s_waitcnt vmcnt(0)" ::: "memory");
        }
        __builtin_amdgcn_sched_barrier(0);
        __builtin_amdgcn_s_barrier();
        const ushortT* Ab = Als[cur];
        const ushortT* Bb = Bls[cur];
#pragma unroll
        for (int ks = 0; ks < 2; ks++) {
            bf16x8 am[4], bv[4];
#pragma unroll
            for (int f = 0; f < 4; f++) {
                am[f] = *(const bf16x8*)&Ab[(wr * 64 + f * 16 + (lane & 15)) * 64 + ks * 32 +
                                            (lane >> 4) * 8];
                bv[f] = *(const bf16x8*)&Bb[(wc * 64 + f * 16 + (lane & 15)) * 64 + ks * 32 +
                                            (lane >> 4) * 8];
            }
#pragma unroll
            for (int fm = 0; fm < 4; fm++)
#pragma unroll
                for (int fn = 0; fn < 4; fn++)
                    acc[fm][fn] = __builtin_amdgcn_mfma_f32_16x16x32_bf16(am[fm], bv[fn],
                                                                          acc[fm][fn], 0, 0, 0);
        }
        asm volatile("" ::: "memory");
        __builtin_amdgcn_s_barrier();
    }

    if (CBF16) {
        ushortT* Cs = (ushortT*)Als;            // 64 x 136 bf16 staging
        const int sr = tid >> 4;                // 0..15 store row
        const int sc8 = (tid & 15) * 8;         // store col group (x8 bf16)
#pragma unroll
        for (int ph = 0; ph < 2; ph++) {
            __syncthreads();
#pragma unroll
            for (int f2 = 0; f2 < 2; f2++) {
                int fm = ph * 2 + f2;
#pragma unroll
                for (int r = 0; r < 4; r++) {
                    int rowt = wr * 64 + fm * 16 + (lane >> 4) * 4 + r;
                    int slot = (rowt & 31) + ((rowt >> 6) << 5);
                    int growY = row0 + rowt;
#pragma unroll
                    for (int fn = 0; fn < 4; fn++) {
                        int col = wc * 64 + fn * 16 + (lane & 15);
                        float v = acc[fm][fn][r];
                        if (GATE) {
                            float yv = bf2f(Yb[(size_t)growY * ldy + col0 + col]);
                            v = yv * v * sigf(v);
                        }
                        if (BIAS) v += bias[col0 + col];
                        Cs[slot * 136 + col] = f2bf(v);
                    }
                }
            }
            __syncthreads();
#pragma unroll
            for (int it = 0; it < 4; it++) {
                int s = it * 16 + sr;
                int rowt = (s & 31) + ph * 32 + ((s >> 5) << 6);
                int growC = row0 + rowt;
                if (FLIPC) {
                    if (doflipC) {
                        int t = growC & (LQ - 1);
                        int ts = (t < len) ? (len - 1 - t) : t;
                        growC = (growC & ~(LQ - 1)) | ts;
                    }
                }
                u16x8 val = *(const u16x8*)&Cs[s * 136 + sc8];
                *(u16x8*)(Cb + (size_t)growC * ldc + col0 + sc8) = val;
            }
        }
    } else {
#pragma unroll
        for (int fm = 0; fm < 4; fm++) {
#pragma unroll
            for (int r = 0; r < 4; r++) {
                int growY = row0 + wr * 64 + fm * 16 + (lane >> 4) * 4 + r;
                int growC = growY;
                if (FLIPC) {
                    if (doflipC) {
                        int t = growC & (LQ - 1);
                        int ts = (t < len) ? (len - 1 - t) : t;
                        growC = (growC & ~(LQ - 1)) | ts;
                    }
                }
#pragma unroll
                for (int fn = 0; fn < 4; fn++) {
                    int col = col0 + wc * 64 + fn * 16 + (lane & 15);
                    if (col < N) {
                        float v = acc[fm][fn][r];
                        float* cp = Cf + (size_t)growC * ldc + col;
                        if (ACC) v += *cp;
                        if (BIAS) v += bias[col];
                        *cp = v;
                    }
                }
            }
        }
    }
}

// ---- causal dw conv (K=4) + SiLU: register-window, 8ch x 32t per thread ----
__global__ __launch_bounds__(256) void k_dwconv(const ushortT* __restrict__ rawx,
                                                const float* __restrict__ cw,
                                                const float* __restrict__ cb,
                                                ushortT* __restrict__ sx) {
    int blk = blockIdx.x;
    int tc = blk & 7;
    int sb = blk >> 3;  // inst*8+b
    int inst = sb >> 3;
    int cg = threadIdx.x & 63;
    int sub = threadIdx.x >> 6;
    int ch0 = cg * 8;
    int t0 = tc * 128 + sub * 32;
    const ushortT* base = rawx + (size_t)sb * LQ * DIQ + ch0;
    ushortT* obase = sx + (size_t)sb * LQ * DIQ + ch0;

    float w[8][4], bs[8];
#pragma unroll
    for (int j = 0; j < 8; j++) {
        float4 wv = *(const float4*)(cw + (size_t)inst * 2048 + (size_t)(ch0 + j) * 4);
        w[j][0] = wv.x; w[j][1] = wv.y; w[j][2] = wv.z; w[j][3] = wv.w;
        bs[j] = cb[inst * DIQ + ch0 + j];
    }
    float x3[8], x2[8], x1[8];
#pragma unroll
    for (int j = 0; j < 8; j++) { x3[j] = 0.f; x2[j] = 0.f; x1[j] = 0.f; }
    if (t0 >= 3) {
        u16x8 v3 = *(const u16x8*)(base + (size_t)(t0 - 3) * DIQ);
        u16x8 v2 = *(const u16x8*)(base + (size_t)(t0 - 2) * DIQ);
        u16x8 v1 = *(const u16x8*)(base + (size_t)(t0 - 1) * DIQ);
#pragma unroll
        for (int j = 0; j < 8; j++) {
            x3[j] = bf2f(v3[j]); x2[j] = bf2f(v2[j]); x1[j] = bf2f(v1[j]);
        }
    }
#pragma unroll 4
    for (int t = t0; t < t0 + 32; t++) {
        u16x8 v = *(const u16x8*)(base + (size_t)t * DIQ);
        float xc[8];
#pragma unroll
        for (int j = 0; j < 8; j++) xc[j] = bf2f(v[j]);
        u16x8 o;
#pragma unroll
        for (int j = 0; j < 8; j++) {
            float acc = bs[j];
            acc = fmaf(w[j][0], x3[j], acc);
            acc = fmaf(w[j][1], x2[j], acc);
            acc = fmaf(w[j][2], x1[j], acc);
            acc = fmaf(w[j][3], xc[j], acc);
            o[j] = f2bf(acc * sigf(acc));
        }
        *(u16x8*)(obase + (size_t)t * DIQ) = o;
#pragma unroll
        for (int j = 0; j < 8; j++) { x3[j] = x2[j]; x2[j] = x1[j]; x1[j] = xc[j]; }
    }
}

// ======== chunked selective scan (CCH=16, packed-f32 fast path) ========
__global__ __launch_bounds__(256) void k_scan1(ushortT* __restrict__ scanX,
                                               const float* __restrict__ xdbl,
                                               const float* __restrict__ dt_w,
                                               const float* __restrict__ dt_b,
                                               const float* __restrict__ A_log,
                                               const float* __restrict__ Dpp,
                                               float* __restrict__ hbuf,
                                               float* __restrict__ sbuf) {
    int bid = blockIdx.x;
    int seq = bid >> 5;          // /(CCH*2)
    int r = bid & 31;
    int c = r >> 1, half = r & 1;
    int inst = seq >> 3;
    int ch = half * 256 + threadIdx.x;

    const float4* xd4 = (const float4*)(xdbl + ((size_t)seq * LQ + c * CT) * 48);
    ushortT* xp = scanX + ((size_t)seq * LQ + c * CT) * DIQ + ch;
    int wo = inst * DIQ + ch;
    float dtw[16], Ad[16];
#pragma unroll
    for (int rr = 0; rr < 16; rr++) dtw[rr] = dt_w[(size_t)wo * 16 + rr];
    float dtb = dt_b[wo];
    bool fastA = true;
#pragma unroll
    for (int n = 0; n < 16; n++) {
        Ad[n] = -__expf(A_log[(size_t)wo * 16 + n]);
        fastA = fastA && (fabsf(Ad[n] + (float)(n + 1)) < 1e-3f * (n + 1));
    }
    float Dd = Dpp[wo];
    float S = 0.f;

    __shared__ float4 sd4[CT * 12];  // 12KB
    for (int u = threadIdx.x; u < CT * 12; u += 256) sd4[u] = xd4[u];
    __syncthreads();

    float h[16];
#pragma unroll
    for (int n = 0; n < 16; n++) h[n] = 0.f;

    float xt = bf2f(xp[0]);
    if (fastA) {
        __attribute__((aligned(16))) f32x2 dtw2[8], h2[8];
#pragma unroll
        for (int p = 0; p < 8; p++) {
            dtw2[p] = (f32x2){dtw[2 * p], dtw[2 * p + 1]};
            h2[p] = (f32x2){0.f, 0.f};
        }
        for (int tl = 0; tl < CT; tl++) {
            float xnext = (tl + 1 < CT) ? bf2f(xp[(size_t)(tl + 1) * DIQ]) : 0.f;
            const float4* s4 = sd4 + tl * 12;
            __attribute__((aligned(16))) f32x2 qq2[8], bb2[8], cc2[8];
            *(float4*)&qq2[0] = s4[0]; *(float4*)&qq2[2] = s4[1];
            *(float4*)&qq2[4] = s4[2]; *(float4*)&qq2[6] = s4[3];
            *(float4*)&bb2[0] = s4[4]; *(float4*)&bb2[2] = s4[5];
            *(float4*)&bb2[4] = s4[6]; *(float4*)&bb2[6] = s4[7];
            *(float4*)&cc2[0] = s4[8]; *(float4*)&cc2[2] = s4[9];
            *(float4*)&cc2[4] = s4[10]; *(float4*)&cc2[6] = s4[11];
            f32x2 dacc = (f32x2){dtb, 0.f};
#pragma unroll
            for (int p = 0; p < 8; p++) dacc = qq2[p] * dtw2[p] + dacc;
            float dt = softplusf(dacc.x + dacc.y);
            S += dt;
            float e1 = __expf(-dt);
            float E = e1 * e1;
            f32x2 ee = (f32x2){e1, E};
            f32x2 E2 = (f32x2){E, E};
            f32x2 dtx2 = (f32x2){dt * xt, dt * xt};
            f32x2 y2 = (f32x2){0.f, 0.f};
#pragma unroll
            for (int p = 0; p < 8; p++) {
                h2[p] = h2[p] * ee + dtx2 * bb2[p];
                y2 = h2[p] * cc2[p] + y2;
                ee = ee * E2;
            }
            xp[(size_t)tl * DIQ] = f2bf(fmaf(xt, Dd, y2.x + y2.y));
            xt = xnext;
        }
#pragma unroll
        for (int p = 0; p < 8; p++) { h[2 * p] = h2[p].x; h[2 * p + 1] = h2[p].y; }
    } else {
        for (int tl = 0; tl < CT; tl++) {
            float xnext = (tl + 1 < CT) ? bf2f(xp[(size_t)(tl + 1) * DIQ]) : 0.f;
            const float4* s4 = sd4 + tl * 12;
            float qq[16], bb[16], cc[16];
            *(float4*)&qq[0] = s4[0]; *(float4*)&qq[4] = s4[1];
            *(float4*)&qq[8] = s4[2]; *(float4*)&qq[12] = s4[3];
            *(float4*)&bb[0] = s4[4]; *(float4*)&bb[4] = s4[5];
            *(float4*)&bb[8] = s4[6]; *(float4*)&bb[12] = s4[7];
            *(float4*)&cc[0] = s4[8]; *(float4*)&cc[4] = s4[9];
            *(float4*)&cc[8] = s4[10]; *(float4*)&cc[12] = s4[11];
            float draw = dtb;
#pragma unroll
            for (int rr = 0; rr < 16; rr++) draw = fmaf(qq[rr], dtw[rr], draw);
            float dt = softplusf(draw);
            S += dt;
            float dtx = dt * xt;
            float y = 0.f;
#pragma unroll
            for (int n = 0; n < 16; n++) {
                float e = __expf(dt * Ad[n]);
                h[n] = fmaf(h[n], e, dtx * bb[n]);
                y = fmaf(h[n], cc[n], y);
            }
            xp[(size_t)tl * DIQ] = f2bf(fmaf(xt, Dd, y));
            xt = xnext;
        }
    }
    size_t hb = ((size_t)(seq * CCH + c) * 16) * DIQ + ch;
#pragma unroll
    for (int n = 0; n < 16; n++) hbuf[hb + (size_t)n * DIQ] = h[n];
    sbuf[(size_t)(seq * CCH + c) * DIQ + ch] = S;
}

__global__ __launch_bounds__(512) void k_scan2(const float* __restrict__ A_log,
                                               float* __restrict__ hbuf,
                                               const float* __restrict__ sbuf) {
    int seq = blockIdx.x;
    int inst = seq >> 3;
    int ch = threadIdx.x;
    int wo = inst * DIQ + ch;
    float Ad[16];
#pragma unroll
    for (int n = 0; n < 16; n++) Ad[n] = -__expf(A_log[(size_t)wo * 16 + n]);
    float hin[16];
#pragma unroll
    for (int n = 0; n < 16; n++) hin[n] = 0.f;
    for (int c = 0; c < CCH; c++) {
        size_t hb = ((size_t)(seq * CCH + c) * 16) * DIQ + ch;
        float Sc = sbuf[(size_t)(seq * CCH + c) * DIQ + ch];
        float he[16];
#pragma unroll
        for (int n = 0; n < 16; n++) he[n] = hbuf[hb + (size_t)n * DIQ];
#pragma unroll
        for (int n = 0; n < 16; n++) hbuf[hb + (size_t)n * DIQ] = hin[n];
#pragma unroll
        for (int n = 0; n < 16; n++) hin[n] = fmaf(hin[n], __expf(Ad[n] * Sc), he[n]);
    }
}

__global__ __launch_bounds__(256) void k_scan3(ushortT* __restrict__ scanX,
                                               const float* __restrict__ xdbl,
                                               const float* __restrict__ dt_w,
                                               const float* __restrict__ dt_b,
                                               const float* __restrict__ A_log,
                                               const float* __restrict__ hbuf) {
    int bid = blockIdx.x;
    int seq = bid / (2 * (CCH - 1));
    int r = bid % (2 * (CCH - 1));
    int c = 1 + (r >> 1), half = r & 1;
    int inst = seq >> 3;
    int ch = half * 256 + threadIdx.x;

    const float4* xd4 = (const float4*)(xdbl + ((size_t)seq * LQ + c * CT) * 48);
    ushortT* xp = scanX + ((size_t)seq * LQ + c * CT) * DIQ + ch;
    int wo = inst * DIQ + ch;
    float dtw[16], Ad[16];
#pragma unroll
    for (int rr = 0; rr < 16; rr++) dtw[rr] = dt_w[(size_t)wo * 16 + rr];
    float dtb = dt_b[wo];
    float amax = -1e30f;
    bool fastA = true;
#pragma unroll
    for (int n = 0; n < 16; n++) {
        Ad[n] = -__expf(A_log[(size_t)wo * 16 + n]);
        amax = fmaxf(amax, Ad[n]);
        fastA = fastA && (fabsf(Ad[n] + (float)(n + 1)) < 1e-3f * (n + 1));
    }
    float hin[16];
    size_t hb = ((size_t)(seq * CCH + c) * 16) * DIQ + ch;
#pragma unroll
    for (int n = 0; n < 16; n++) hin[n] = hbuf[hb + (size_t)n * DIQ];

    __shared__ float4 sd4[CT * 12];
    for (int u = threadIdx.x; u < CT * 12; u += 256) sd4[u] = xd4[u];
    __syncthreads();

    if (fastA) {
        __attribute__((aligned(16))) f32x2 dtw2[8], hin2[8];
#pragma unroll
        for (int p = 0; p < 8; p++) {
            dtw2[p] = (f32x2){dtw[2 * p], dtw[2 * p + 1]};
            hin2[p] = (f32x2){hin[2 * p], hin[2 * p + 1]};
        }
        float S = 0.f;
        for (int tl = 0; tl < CT; tl++) {
            const float4* s4 = sd4 + tl * 12;
            __attribute__((aligned(16))) f32x2 qq2[8], cc2[8];
            *(float4*)&qq2[0] = s4[0]; *(float4*)&qq2[2] = s4[1];
            *(float4*)&qq2[4] = s4[2]; *(float4*)&qq2[6] = s4[3];
            f32x2 dacc = (f32x2){dtb, 0.f};
#pragma unroll
            for (int p = 0; p < 8; p++) dacc = qq2[p] * dtw2[p] + dacc;
            S += softplusf(dacc.x + dacc.y);
            if (__all(-S < -30.f)) break;  // amax ≈ -1 in fastA
            *(float4*)&cc2[0] = s4[8]; *(float4*)&cc2[2] = s4[9];
            *(float4*)&cc2[4] = s4[10]; *(float4*)&cc2[6] = s4[11];
            float eS = __expf(-S);
            float E = eS * eS;
            f32x2 ee = (f32x2){eS, E};
            f32x2 E2 = (f32x2){E, E};
            f32x2 corr2 = (f32x2){0.f, 0.f};
#pragma unroll
            for (int p = 0; p < 8; p++) {
                corr2 = (ee * hin2[p]) * cc2[p] + corr2;
                ee = ee * E2;
            }
            xp[(size_t)tl * DIQ] = f2bf(bf2f(xp[(size_t)tl * DIQ]) + corr2.x + corr2.y);
        }
    } else {
        float S = 0.f;
        for (int tl = 0; tl < CT; tl++) {
            const float4* s4 = sd4 + tl * 12;
            float qq[16], cc[16];
            *(float4*)&qq[0] = s4[0]; *(float4*)&qq[4] = s4[1];
            *(float4*)&qq[8] = s4[2]; *(float4*)&qq[12] = s4[3];
            float draw = dtb;
#pragma unroll
            for (int rr = 0; rr < 16; rr++) draw = fmaf(qq[rr], dtw[rr], draw);
            S += softplusf(draw);
            if (__all(amax * S < -30.f)) break;
            *(float4*)&cc[0] = s4[8]; *(float4*)&cc[4] = s4[9];
            *(float4*)&cc[8] = s4[10]; *(float4*)&cc[12] = s4[11];
            float corr = 0.f;
#pragma unroll
            for (int n = 0; n < 16; n++)
                corr = fmaf(__expf(Ad[n] * S) * hin[n], cc[n], corr);
            xp[(size_t)tl * DIQ] = f2bf(bf2f(xp[(size_t)tl * DIQ]) + corr);
        }
    }
}

// ---------------- stage-1 mean/max over L (moutb bf16 input) ----------------
__global__ void k_redu1(const ushortT* __restrict__ mo, float* __restrict__ psum,
                        float* __restrict__ pmax) {
    int b = blockIdx.x >> 5, tc = blockIdx.x & 31;  // 192 threads
    int ch0 = threadIdx.x * 4;
    const ushortT* p = mo + ((size_t)b * LQ + tc * 32) * DMQ + ch0;
    float s[4] = {0.f, 0.f, 0.f, 0.f};
    float m[4] = {-3.4e38f, -3.4e38f, -3.4e38f, -3.4e38f};
    for (int t = 0; t < 32; t++) {
        ushort4 v = *(const ushort4*)(p + (size_t)t * DMQ);
        float f0 = bf2f(v.x), f1 = bf2f(v.y), f2 = bf2f(v.z), f3 = bf2f(v.w);
        s[0] += f0; s[1] += f1; s[2] += f2; s[3] += f3;
        m[0] = fmaxf(m[0], f0); m[1] = fmaxf(m[1], f1);
        m[2] = fmaxf(m[2], f2); m[3] = fmaxf(m[3], f3);
    }
    *(float4*)(psum + (size_t)(b * 32 + tc) * DMQ + ch0) = *(float4*)s;
    *(float4*)(pmax + (size_t)(b * 32 + tc) * DMQ + ch0) = *(float4*)m;
}

__global__ void k_redu2(const float* __restrict__ psum, const float* __restrict__ pmax,
                        float* __restrict__ avg, float* __restrict__ mx) {
    int idx = blockIdx.x * 256 + threadIdx.x;  // 0..6143
    int b = idx / DMQ, ch = idx % DMQ;
    float s = 0.f, m = -3.4e38f;
    for (int tc = 0; tc < 32; tc++) {
        s += psum[(size_t)(b * 32 + tc) * DMQ + ch];
        m = fmaxf(m, pmax[(size_t)(b * 32 + tc) * DMQ + ch]);
    }
    avg[idx] = s * (1.f / LQ);
    mx[idx] = m;
}

// ---- hs[b][j]: wave-per-output GEMV ----
__global__ __launch_bounds__(256) void k_att1(const float* __restrict__ avg,
                                              const float* __restrict__ mx,
                                              const float* __restrict__ w1,
                                              float* __restrict__ hs) {
    int gw = (blockIdx.x * 256 + threadIdx.x) >> 6;  // 0..3071
    int lane = threadIdx.x & 63;
    int b = gw / 384, j = gw % 384;
    const float* w = w1 + (size_t)j * DMQ;
    const float* a = avg + (size_t)b * DMQ;
    const float* m2 = mx + (size_t)b * DMQ;
    float s1 = 0.f, s2 = 0.f;
#pragma unroll
    for (int it = 0; it < 3; it++) {
        int k = it * 256 + lane * 4;
        float4 wv = *(const float4*)(w + k);
        float4 av = *(const float4*)(a + k);
        float4 mv = *(const float4*)(m2 + k);
        s1 = fmaf(av.x, wv.x, s1); s1 = fmaf(av.y, wv.y, s1);
        s1 = fmaf(av.z, wv.z, s1); s1 = fmaf(av.w, wv.w, s1);
        s2 = fmaf(mv.x, wv.x, s2); s2 = fmaf(mv.y, wv.y, s2);
        s2 = fmaf(mv.z, wv.z, s2); s2 = fmaf(mv.w, wv.w, s2);
    }
#pragma unroll
    for (int o = 32; o > 0; o >>= 1) {
        s1 += __shfl_xor(s1, o);
        s2 += __shfl_xor(s2, o);
    }
    if (lane == 0) hs[gw] = fmaxf(s1, 0.f) + fmaxf(s2, 0.f);
}

// ---- att[b][n]: wave-per-output GEMV ----
__global__ __launch_bounds__(256) void k_att2(const float* __restrict__ hs,
                                              const float* __restrict__ w2,
                                              float* __restrict__ att) {
    int gw = (blockIdx.x * 256 + threadIdx.x) >> 6;  // 0..6143
    int lane = threadIdx.x & 63;
    int b = gw / DMQ, n = gw % DMQ;
    const float* w = w2 + (size_t)n * 384;
    const float* h = hs + (size_t)b * 384;
    float s = 0.f;
#pragma unroll
    for (int it = 0; it < 3; it++) {
        int k = it * 128 + lane * 2;
        float2 wv = *(const float2*)(w + k);
        float2 hv = *(const float2*)(h + k);
        s = fmaf(hv.x, wv.x, s);
        s = fmaf(hv.y, wv.y, s);
    }
#pragma unroll
    for (int o = 32; o > 0; o >>= 1) s += __shfl_xor(s, o);
    if (lane == 0) att[gw] = sigf(s);
}

__global__ void k_diag(float* __restrict__ o, float v) {
    if (blockIdx.x == 0 && threadIdx.x == 0) o[0] = v;
}

extern "C" void kernel_launch(void* const* d_in, const int* in_sizes, int n_in, void* d_out,
                              int out_size, void* d_ws, size_t ws_size, hipStream_t stream) {
    (void)in_sizes; (void)n_in; (void)out_size;
    const float* hid = (const float*)d_in[0];
    const int* mask = (const int*)d_in[1];
    const float* pool_w = (const float*)d_in[2];
    const float* pool_b = (const float*)d_in[3];
    const float* bn_g = (const float*)d_in[4];
    const float* bn_b = (const float*)d_in[5];
    const float* bn_rm = (const float*)d_in[6];
    const float* bn_rv = (const float*)d_in[7];
    const float* ipw = (const float*)d_in[8];
    const float* cw = (const float*)d_in[9];
    const float* cb = (const float*)d_in[10];
    const float* xpw = (const float*)d_in[11];
    const float* dtw = (const float*)d_in[12];
    const float* dtb = (const float*)d_in[13];
    const float* alog = (const float*)d_in[14];
    const float* Dpp = (const float*)d_in[15];
    const float* mow = (const float*)d_in[16];
    const float* opw = (const float*)d_in[17];
    const float* opb = (const float*)d_in[18];
    const float* caw1 = (const float*)d_in[19];
    const float* caw2 = (const float*)d_in[20];
    const float* fusw = (const float*)d_in[21];
    const float* fusb = (const float*)d_in[22];
    float* out = (float*)d_out;

    // workspace layout (float-equivalent offsets)
    const size_t O_IPWB = 32768;
    const size_t O_XPWB = 819200;
    const size_t O_FUSWB = 1015808;
    const size_t O_WTMPB = 1310720;
    const size_t O_XDBL = 1703936;
    const size_t O_CBASE = 4063232;   // cbase bf16 / later moutb bf16
    const size_t O_RAWX = 7208960;    // rawx / hbuf+sbuf / gbuf
    const size_t O_SCANX = 19791872;  // scanX bf16 / later psum+pmax+fuswb8
    const size_t TOTAL_F = 32374784;  // 129.5 MB
    if (ws_size < TOTAL_F * 4) {
        k_diag<<<1, 64, 0, stream>>>(out, (float)(ws_size >> 20));
        return;
    }

    float* ws = (float*)d_ws;
    int* lengths = (int*)ws;
    float* att = ws + 1024;
    float* avg = att + 6144;
    float* mxp = avg + 6144;
    float* hs = mxp + 6144;
    ushortT* ipwb = (ushortT*)(ws + O_IPWB);
    ushortT* xpwb = (ushortT*)(ws + O_XPWB);
    ushortT* fuswb = (ushortT*)(ws + O_FUSWB);
    ushortT* wtmpb = (ushortT*)(ws + O_WTMPB);
    float* xdbl = ws + O_XDBL;
    ushortT* cbase = (ushortT*)(ws + O_CBASE);
    ushortT* rawx = (ushortT*)(ws + O_RAWX);
    ushortT* scanX = (ushortT*)(ws + O_SCANX);
    // overlays
    float* hbuf = ws + O_RAWX;            // rawx dead after dwconv; 48*16*16*512=6291456 f
    float* sbuf = hbuf + 6291456;         // +393216 f  (total 6684672 <= 12582912 capacity)
    ushortT* gbuf = rawx;                 // hbuf/sbuf dead after scan3
    ushortT* moutb = cbase;               // cbase dead after z-GEMM
    float* psum = ws + O_SCANX;           // scanX dead after z-GEMM
    float* pmax = psum + 196608;
    ushortT* fuswb8 = (ushortT*)(pmax + 196608);  // fits in scanX region

    // ---- prep ----
    k_lengths<<<dim3(8), dim3(256), 0, stream>>>(mask, lengths);
    k_prep<<<dim3(9984), dim3(256), 0, stream>>>(ipw, fusw, xpw, ipwb, fuswb, xpwb);
    k_wfuse<<<dim3(768), dim3(256), 0, stream>>>(opw, mow, wtmpb);

    // ---- pool (all scales) ----
    k_pool<<<dim3(3 * 8192), dim3(64), 0, stream>>>(hid, pool_w, pool_b, bn_g, bn_b, bn_rm,
                                                    bn_rv, cbase);

    // ---- in_proj x-half (all 6 insts), flip odd insts ----
    gemm_bf16<2, 0, 0, 0, 1, 0><<<dim3(4, 64, 6), 256, 0, stream>>>(
        cbase, ipwb, rawx, nullptr, nullptr, lengths, 512, 256, 256, 512, 0, 2097152, 1,
        262144, 4194304, 0, 0, 0, 0);

    // ---- dwconv + SiLU ----
    k_dwconv<<<dim3(384), dim3(256), 0, stream>>>(rawx, cw, cb, scanX);

    // ---- x_proj ----
    gemm_bf16<0, 0, 0, 0, 0, 0><<<dim3(1, 64, 6), 256, 0, stream>>>(
        scanX, xpwb, xdbl, nullptr, nullptr, lengths, 48, 512, 512, 48, 0, 4194304, 0, 65536,
        393216, 0, 0, 0, 0);

    // ---- chunked selective scan (in place on scanX) ----
    k_scan1<<<dim3(48 * CCH * 2), dim3(256), 0, stream>>>(scanX, xdbl, dtw, dtb, alog, Dpp,
                                                          hbuf, sbuf);
    k_scan2<<<dim3(48), dim3(512), 0, stream>>>(alog, hbuf, sbuf);
    k_scan3<<<dim3(48 * (CCH - 1) * 2), dim3(256), 0, stream>>>(scanX, xdbl, dtw, dtb, alog,
                                                                hbuf);

    // ---- in_proj z-half + gate epilogue -> gbuf (dir-interleaved, unflip-scatter) ----
    gemm_bf16<2, 2, 0, 0, 1, 1><<<dim3(4, 64, 6), 256, 0, stream>>>(
        cbase, ipwb + 131072, gbuf, nullptr, scanX, lengths, 512, 256, 256, 1024, 512,
        2097152, 1, 262144, 8388608, 512, 1, 4194304, 0);

    // ---- single fused mo+op GEMM (K=1024) -> moutb bf16 (+bias) ----
    gemm_bf16<0, 0, 1, 0, 1, 0><<<dim3(2, 64, 3), 256, 0, stream>>>(
        gbuf, wtmpb, moutb, opb, nullptr, lengths, 256, 1024, 1024, 768, 0, 8388608, 0,
        262144, 256, 0, 0, 0, 256);

    // ---- attention pooling -> per-batch scaled fus weight -> final projection ----
    k_redu1<<<dim3(256), dim3(192), 0, stream>>>(moutb, psum, pmax);
    k_redu2<<<dim3(24), dim3(256), 0, stream>>>(psum, pmax, avg, mxp);
    k_att1<<<dim3(768), dim3(256), 0, stream>>>(avg, mxp, caw1, hs);
    k_att2<<<dim3(1536), dim3(256), 0, stream>>>(hs, caw2, att);
    k_fusw8<<<dim3(4608), dim3(256), 0, stream>>>(fusw, att, fuswb8);
    gemm_bf16<0, 0, 1, 0, 0, 0><<<dim3(6, 8, 8), 256, 0, stream>>>(
        moutb, fuswb8, out, fusb, nullptr, lengths, DMQ, DMQ, DMQ, DMQ, 0, 786432, 0, 589824,
        786432, 0, 0, 0, 0);
}

// Round 18
// 369.046 us; speedup vs baseline: 1.0558x; 1.0558x over previous
//
#include <hip/hip_runtime.h>
#include <cstddef>
#include <cstdint>

#define LQ 1024
#define DMQ 768
#define DSQ 256
#define DIQ 512
#define CCH 8
#define CT (LQ / CCH)

typedef unsigned short ushortT;
using f32x4 = __attribute__((ext_vector_type(4))) float;
using f32x2 = __attribute__((ext_vector_type(2))) float;
using bf16x8 = __attribute__((ext_vector_type(8))) short;
using u16x8 = __attribute__((ext_vector_type(8))) unsigned short;

__device__ __forceinline__ float sigf(float x) { return 1.f / (1.f + __expf(-x)); }
__device__ __forceinline__ float softplusf(float x) {
    return fmaxf(x, 0.f) + __logf(1.f + __expf(-fabsf(x)));
}
__device__ __forceinline__ ushortT f2bf(float f) {
    unsigned u = __float_as_uint(f);
    u += 0x7FFFu + ((u >> 16) & 1u);
    return (ushortT)(u >> 16);
}
__device__ __forceinline__ float bf2f(ushortT u) {
    return __uint_as_float(((unsigned)u) << 16);
}
__device__ __forceinline__ void gload_lds16(const void* g, void* l) {
    __builtin_amdgcn_global_load_lds((const __attribute__((address_space(1))) void*)g,
                                     (__attribute__((address_space(3))) void*)l, 16, 0, 0);
}

// ---------------- lengths ----------------
__global__ void k_lengths(const int* __restrict__ mask, int* __restrict__ lengths) {
    int b = blockIdx.x;
    int s = 0;
    for (int t = threadIdx.x; t < LQ; t += 256) s += mask[b * LQ + t];
    __shared__ int sm[256];
    sm[threadIdx.x] = s;
    __syncthreads();
    for (int o = 128; o > 0; o >>= 1) {
        if (threadIdx.x < o) sm[threadIdx.x] += sm[threadIdx.x + o];
        __syncthreads();
    }
    if (threadIdx.x == 0) lengths[b] = sm[0];
}

// ---------------- merged weight conversion ----------------
__global__ void k_prep(const float* __restrict__ ipw, const float* __restrict__ fusw,
                       const float* __restrict__ xpw, ushortT* __restrict__ ipwb,
                       ushortT* __restrict__ fuswb, ushortT* __restrict__ xpwb) {
    int i = blockIdx.x * 256 + threadIdx.x;
    if (i < 1572864) { ipwb[i] = f2bf(ipw[i]); return; }
    i -= 1572864;
    if (i < 589824) { fuswb[i] = f2bf(fusw[i]); return; }
    i -= 589824;
    if (i >= 393216) return;
    int inst = i >> 16, rem = i & 65535;
    int row = rem >> 9, col = rem & 511;
    float v = (row < 48) ? xpw[((size_t)inst * 48 + row) * 512 + col] : 0.f;
    xpwb[i] = f2bf(v);
}

// -------- fused weight, dir-interleaved: wf2[i][m][dir*512+d] --------
__global__ void k_wfuse(const float* __restrict__ opw, const float* __restrict__ mow,
                        ushortT* __restrict__ wf) {
    int idx = blockIdx.x * 256 + threadIdx.x;  // 196608 = 6*256*128
    int inst = idx >> 15;
    int rem = idx & 32767;
    int m = rem >> 7;
    int d0 = (rem & 127) * 4;
    int i = inst >> 1, dir = inst & 1;
    const float* a = opw + (size_t)i * 131072 + dir * 256 + (size_t)m * 512;
    const float* bm = mow + (size_t)inst * 131072 + d0;
    float s0 = 0.f, s1 = 0.f, s2 = 0.f, s3 = 0.f;
    for (int c = 0; c < 256; c++) {
        float av = a[c];
        float4 bv = *(const float4*)(bm + (size_t)c * 512);
        s0 = fmaf(av, bv.x, s0);
        s1 = fmaf(av, bv.y, s1);
        s2 = fmaf(av, bv.z, s2);
        s3 = fmaf(av, bv.w, s3);
    }
    ushort4 r = {f2bf(s0), f2bf(s1), f2bf(s2), f2bf(s3)};
    *(ushort4*)(wf + ((size_t)i * 256 + m) * 1024 + dir * 512 + d0) = r;
}

// -------- per-batch att-scaled fus weight --------
__global__ void k_fusw8(const float* __restrict__ fusw, const float* __restrict__ att,
                        ushortT* __restrict__ wf8) {
    int idx = blockIdx.x * 256 + threadIdx.x;  // 8*768*192
    int b = idx / 147456;
    int rem = idx % 147456;
    int n = rem / 192;
    int k0 = (rem % 192) * 4;
    float4 w = *(const float4*)(fusw + (size_t)n * 768 + k0);
    float4 a = *(const float4*)(att + (size_t)b * 768 + k0);
    ushort4 r = {f2bf(w.x * a.x), f2bf(w.y * a.y), f2bf(w.z * a.z), f2bf(w.w * a.w)};
    *(ushort4*)(wf8 + ((size_t)(b * 768 + n)) * 768 + k0) = r;
}

// ------- dilated dw conv + BN + GELU -> c bf16 (all 3 scales, float4/thread) -------
__global__ __launch_bounds__(64) void k_pool(const float* __restrict__ hid,
                                             const float* __restrict__ pw,
                                             const float* __restrict__ pb,
                                             const float* __restrict__ bg,
                                             const float* __restrict__ bb,
                                             const float* __restrict__ brm,
                                             const float* __restrict__ brv,
                                             ushortT* __restrict__ cdst) {
    int gidx = blockIdx.x;  // 3*8192
    int isc = gidx >> 13;
    int idx = gidx & 8191;
    int l = idx & (LQ - 1);
    int b = idx >> 10;
    int ch0 = threadIdx.x * 4;
    int dil = 1 << isc;
    int wci0 = isc * DSQ + ch0;
    const float* xb = hid + (size_t)b * LQ * DMQ + isc * DSQ + ch0;
    float wv[12];
    *(float4*)&wv[0] = *(const float4*)(pw + (size_t)wci0 * 3);
    *(float4*)&wv[4] = *(const float4*)(pw + (size_t)wci0 * 3 + 4);
    *(float4*)&wv[8] = *(const float4*)(pw + (size_t)wci0 * 3 + 8);
    float pbv[4], bgv[4], bbv[4], rmv[4], rvv[4];
    *(float4*)pbv = *(const float4*)(pb + wci0);
    *(float4*)bgv = *(const float4*)(bg + wci0);
    *(float4*)bbv = *(const float4*)(bb + wci0);
    *(float4*)rmv = *(const float4*)(brm + wci0);
    *(float4*)rvv = *(const float4*)(brv + wci0);
    float xm[4] = {0.f, 0.f, 0.f, 0.f}, xc[4], xp[4] = {0.f, 0.f, 0.f, 0.f};
    int lm = l - dil, lp = l + dil;
    if (lm >= 0) *(float4*)xm = *(const float4*)(xb + (size_t)lm * DMQ);
    *(float4*)xc = *(const float4*)(xb + (size_t)l * DMQ);
    if (lp < LQ) *(float4*)xp = *(const float4*)(xb + (size_t)lp * DMQ);
    ushort4 o;
#pragma unroll
    for (int j = 0; j < 4; j++) {
        float acc = pbv[j];
        acc = fmaf(wv[j * 3 + 0], xm[j], acc);
        acc = fmaf(wv[j * 3 + 1], xc[j], acc);
        acc = fmaf(wv[j * 3 + 2], xp[j], acc);
        float xn = (acc - rmv[j]) * rsqrtf(rvv[j] + 1e-5f) * bgv[j] + bbv[j];
        float y = 0.5f * xn * (1.0f + erff(xn * 0.70710678118654752f));
        ((ushortT*)&o)[j] = f2bf(y);
    }
    *(ushort4*)(cdst + (size_t)isc * 2097152 + (size_t)idx * DSQ + ch0) = o;
}

// ---------------- batched bf16 GEMM: dbuf pipeline + LDS-transpose bf16 epilogue -------
template <int FLIPA, int FLIPC, int BIAS, int ACC, int CBF16, int GATE>
__global__ __launch_bounds__(256) void gemm_bf16(
    const ushortT* __restrict__ A, const ushortT* __restrict__ Bw, void* __restrict__ Cv,
    const float* __restrict__ bias, const ushortT* __restrict__ Yb,
    const int* __restrict__ lengths, int N, int Kd, int lda, int ldc, int ldy, long sAz,
    int zshiftA, long sBz, long sCz, long sCzOdd, int zshiftC, long sYz, int sBiasz) {
    __shared__ ushortT Als[2][8192];
    __shared__ ushortT Bls[2][8192];
    const int z = blockIdx.z;
    A += (size_t)(z >> zshiftA) * sAz;
    Bw += (size_t)z * sBz;
    size_t cbase = (size_t)(z >> zshiftC) * sCz +
                   (size_t)(z & ((1 << zshiftC) - 1)) * sCzOdd;
    float* Cf = (float*)Cv + (CBF16 ? 0 : cbase);
    ushortT* Cb = (ushortT*)Cv + (CBF16 ? cbase : 0);
    if (BIAS) bias += (size_t)z * sBiasz;
    if (GATE) Yb += (size_t)z * sYz;

    const int tid = threadIdx.x;
    const int lane = tid & 63;
    const int wave = tid >> 6;
    const int wr = wave >> 1, wc = wave & 1;
    const int row0 = blockIdx.y * 128, col0 = blockIdx.x * 128;
    const bool doflipA = (FLIPA == 1) || (FLIPA == 2 && (z & 1));
    const bool doflipC = (FLIPC == 1) || (FLIPC == 2 && (z & 1));
    int len = 0;
    if (FLIPA || FLIPC) len = lengths[row0 >> 10];

    const int srow = wave * 8 + (lane >> 3);  // + it*32
    const int scol = (lane & 7) * 8;

    auto stage = [&](int buf, int k0) {
#pragma unroll
        for (int it = 0; it < 4; it++) {
            int row = it * 32 + srow;
            int grow = row0 + row;
            if (FLIPA) {
                if (doflipA) {
                    int t = grow & (LQ - 1);
                    int ts = (t < len) ? (len - 1 - t) : t;
                    grow = (grow & ~(LQ - 1)) | ts;
                }
            }
            gload_lds16(A + (size_t)grow * lda + k0 + scol,
                        &Als[buf][it * 2048 + wave * 512]);
        }
#pragma unroll
        for (int it = 0; it < 4; it++) {
            int row = it * 32 + srow;
            gload_lds16(Bw + (size_t)(col0 + row) * Kd + k0 + scol,
                        &Bls[buf][it * 2048 + wave * 512]);
        }
    };

    f32x4 acc[4][4];
#pragma unroll
    for (int i = 0; i < 4; i++)
#pragma unroll
        for (int j = 0; j < 4; j++) acc[i][j] = (f32x4){0.f, 0.f, 0.f, 0.f};

    const int niter = Kd >> 6;
    stage(0, 0);
    for (int it = 0; it < niter; ++it) {
        const int cur = it & 1;
        if (it + 1 < niter) {
            stage(cur ^ 1, (it + 1) << 6);
            asm volatile("s_waitcnt vmcnt(8)" ::: "memory");
        } else {
            asm volatile("s_waitcnt vmcnt(0)" ::: "memory");
        }
        __builtin_amdgcn_sched_barrier(0);
        __builtin_amdgcn_s_barrier();
        const ushortT* Ab = Als[cur];
        const ushortT* Bb = Bls[cur];
#pragma unroll
        for (int ks = 0; ks < 2; ks++) {
            bf16x8 am[4], bv[4];
#pragma unroll
            for (int f = 0; f < 4; f++) {
                am[f] = *(const bf16x8*)&Ab[(wr * 64 + f * 16 + (lane & 15)) * 64 + ks * 32 +
                                            (lane >> 4) * 8];
                bv[f] = *(const bf16x8*)&Bb[(wc * 64 + f * 16 + (lane & 15)) * 64 + ks * 32 +
                                            (lane >> 4) * 8];
            }
#pragma unroll
            for (int fm = 0; fm < 4; fm++)
#pragma unroll
                for (int fn = 0; fn < 4; fn++)
                    acc[fm][fn] = __builtin_amdgcn_mfma_f32_16x16x32_bf16(am[fm], bv[fn],
                                                                          acc[fm][fn], 0, 0, 0);
        }
        asm volatile("" ::: "memory");
        __builtin_amdgcn_s_barrier();
    }

    if (CBF16) {
        ushortT* Cs = (ushortT*)Als;            // 64 x 136 bf16 staging
        const int sr = tid >> 4;                // 0..15 store row
        const int sc8 = (tid & 15) * 8;         // store col group (x8 bf16)
#pragma unroll
        for (int ph = 0; ph < 2; ph++) {
            __syncthreads();
#pragma unroll
            for (int f2 = 0; f2 < 2; f2++) {
                int fm = ph * 2 + f2;
#pragma unroll
                for (int r = 0; r < 4; r++) {
                    int rowt = wr * 64 + fm * 16 + (lane >> 4) * 4 + r;
                    int slot = (rowt & 31) + ((rowt >> 6) << 5);
                    int growY = row0 + rowt;
#pragma unroll
                    for (int fn = 0; fn < 4; fn++) {
                        int col = wc * 64 + fn * 16 + (lane & 15);
                        float v = acc[fm][fn][r];
                        if (GATE) {
                            float yv = bf2f(Yb[(size_t)growY * ldy + col0 + col]);
                            v = yv * v * sigf(v);
                        }
                        if (BIAS) v += bias[col0 + col];
                        Cs[slot * 136 + col] = f2bf(v);
                    }
                }
            }
            __syncthreads();
#pragma unroll
            for (int it = 0; it < 4; it++) {
                int s = it * 16 + sr;
                int rowt = (s & 31) + ph * 32 + ((s >> 5) << 6);
                int growC = row0 + rowt;
                if (FLIPC) {
                    if (doflipC) {
                        int t = growC & (LQ - 1);
                        int ts = (t < len) ? (len - 1 - t) : t;
                        growC = (growC & ~(LQ - 1)) | ts;
                    }
                }
                u16x8 val = *(const u16x8*)&Cs[s * 136 + sc8];
                *(u16x8*)(Cb + (size_t)growC * ldc + col0 + sc8) = val;
            }
        }
    } else {
#pragma unroll
        for (int fm = 0; fm < 4; fm++) {
#pragma unroll
            for (int r = 0; r < 4; r++) {
                int growY = row0 + wr * 64 + fm * 16 + (lane >> 4) * 4 + r;
                int growC = growY;
                if (FLIPC) {
                    if (doflipC) {
                        int t = growC & (LQ - 1);
                        int ts = (t < len) ? (len - 1 - t) : t;
                        growC = (growC & ~(LQ - 1)) | ts;
                    }
                }
#pragma unroll
                for (int fn = 0; fn < 4; fn++) {
                    int col = col0 + wc * 64 + fn * 16 + (lane & 15);
                    if (col < N) {
                        float v = acc[fm][fn][r];
                        float* cp = Cf + (size_t)growC * ldc + col;
                        if (ACC) v += *cp;
                        if (BIAS) v += bias[col];
                        *cp = v;
                    }
                }
            }
        }
    }
}

// ---- causal dw conv (K=4) + SiLU: register-window, 8ch x 32t per thread ----
__global__ __launch_bounds__(256) void k_dwconv(const ushortT* __restrict__ rawx,
                                                const float* __restrict__ cw,
                                                const float* __restrict__ cb,
                                                ushortT* __restrict__ sx) {
    int blk = blockIdx.x;
    int tc = blk & 7;
    int sb = blk >> 3;  // inst*8+b
    int inst = sb >> 3;
    int cg = threadIdx.x & 63;
    int sub = threadIdx.x >> 6;
    int ch0 = cg * 8;
    int t0 = tc * 128 + sub * 32;
    const ushortT* base = rawx + (size_t)sb * LQ * DIQ + ch0;
    ushortT* obase = sx + (size_t)sb * LQ * DIQ + ch0;

    float w[8][4], bs[8];
#pragma unroll
    for (int j = 0; j < 8; j++) {
        float4 wv = *(const float4*)(cw + (size_t)inst * 2048 + (size_t)(ch0 + j) * 4);
        w[j][0] = wv.x; w[j][1] = wv.y; w[j][2] = wv.z; w[j][3] = wv.w;
        bs[j] = cb[inst * DIQ + ch0 + j];
    }
    float x3[8], x2[8], x1[8];
#pragma unroll
    for (int j = 0; j < 8; j++) { x3[j] = 0.f; x2[j] = 0.f; x1[j] = 0.f; }
    if (t0 >= 3) {
        u16x8 v3 = *(const u16x8*)(base + (size_t)(t0 - 3) * DIQ);
        u16x8 v2 = *(const u16x8*)(base + (size_t)(t0 - 2) * DIQ);
        u16x8 v1 = *(const u16x8*)(base + (size_t)(t0 - 1) * DIQ);
#pragma unroll
        for (int j = 0; j < 8; j++) {
            x3[j] = bf2f(v3[j]); x2[j] = bf2f(v2[j]); x1[j] = bf2f(v1[j]);
        }
    }
#pragma unroll 4
    for (int t = t0; t < t0 + 32; t++) {
        u16x8 v = *(const u16x8*)(base + (size_t)t * DIQ);
        float xc[8];
#pragma unroll
        for (int j = 0; j < 8; j++) xc[j] = bf2f(v[j]);
        u16x8 o;
#pragma unroll
        for (int j = 0; j < 8; j++) {
            float acc = bs[j];
            acc = fmaf(w[j][0], x3[j], acc);
            acc = fmaf(w[j][1], x2[j], acc);
            acc = fmaf(w[j][2], x1[j], acc);
            acc = fmaf(w[j][3], xc[j], acc);
            o[j] = f2bf(acc * sigf(acc));
        }
        *(u16x8*)(obase + (size_t)t * DIQ) = o;
#pragma unroll
        for (int j = 0; j < 8; j++) { x3[j] = x2[j]; x2[j] = x1[j]; x1[j] = xc[j]; }
    }
}

// ======== chunked selective scan (CCH=8, packed-f32 fast path) ========
__global__ __launch_bounds__(256) void k_scan1(ushortT* __restrict__ scanX,
                                               const float* __restrict__ xdbl,
                                               const float* __restrict__ dt_w,
                                               const float* __restrict__ dt_b,
                                               const float* __restrict__ A_log,
                                               const float* __restrict__ Dpp,
                                               float* __restrict__ hbuf,
                                               float* __restrict__ sbuf) {
    int bid = blockIdx.x;
    int seq = bid >> 4;
    int r = bid & 15;
    int c = r >> 1, half = r & 1;
    int inst = seq >> 3;
    int ch = half * 256 + threadIdx.x;

    const float4* xd4 = (const float4*)(xdbl + ((size_t)seq * LQ + c * CT) * 48);
    ushortT* xp = scanX + ((size_t)seq * LQ + c * CT) * DIQ + ch;
    int wo = inst * DIQ + ch;
    float dtw[16], Ad[16];
#pragma unroll
    for (int rr = 0; rr < 16; rr++) dtw[rr] = dt_w[(size_t)wo * 16 + rr];
    float dtb = dt_b[wo];
    bool fastA = true;
#pragma unroll
    for (int n = 0; n < 16; n++) {
        Ad[n] = -__expf(A_log[(size_t)wo * 16 + n]);
        fastA = fastA && (fabsf(Ad[n] + (float)(n + 1)) < 1e-3f * (n + 1));
    }
    float Dd = Dpp[wo];
    float S = 0.f;

    __shared__ float4 sd4[CT * 12];  // 24KB
    for (int u = threadIdx.x; u < CT * 12; u += 256) sd4[u] = xd4[u];
    __syncthreads();

    float h[16];
#pragma unroll
    for (int n = 0; n < 16; n++) h[n] = 0.f;

    float xt = bf2f(xp[0]);
    if (fastA) {
        __attribute__((aligned(16))) f32x2 dtw2[8], h2[8];
#pragma unroll
        for (int p = 0; p < 8; p++) {
            dtw2[p] = (f32x2){dtw[2 * p], dtw[2 * p + 1]};
            h2[p] = (f32x2){0.f, 0.f};
        }
        for (int tl = 0; tl < CT; tl++) {
            float xnext = (tl + 1 < CT) ? bf2f(xp[(size_t)(tl + 1) * DIQ]) : 0.f;
            const float4* s4 = sd4 + tl * 12;
            __attribute__((aligned(16))) f32x2 qq2[8], bb2[8], cc2[8];
            *(float4*)&qq2[0] = s4[0]; *(float4*)&qq2[2] = s4[1];
            *(float4*)&qq2[4] = s4[2]; *(float4*)&qq2[6] = s4[3];
            *(float4*)&bb2[0] = s4[4]; *(float4*)&bb2[2] = s4[5];
            *(float4*)&bb2[4] = s4[6]; *(float4*)&bb2[6] = s4[7];
            *(float4*)&cc2[0] = s4[8]; *(float4*)&cc2[2] = s4[9];
            *(float4*)&cc2[4] = s4[10]; *(float4*)&cc2[6] = s4[11];
            f32x2 dacc = (f32x2){dtb, 0.f};
#pragma unroll
            for (int p = 0; p < 8; p++) dacc = qq2[p] * dtw2[p] + dacc;
            float dt = softplusf(dacc.x + dacc.y);
            S += dt;
            float e1 = __expf(-dt);
            float E = e1 * e1;
            f32x2 ee = (f32x2){e1, E};
            f32x2 E2 = (f32x2){E, E};
            f32x2 dtx2 = (f32x2){dt * xt, dt * xt};
            f32x2 y2 = (f32x2){0.f, 0.f};
#pragma unroll
            for (int p = 0; p < 8; p++) {
                h2[p] = h2[p] * ee + dtx2 * bb2[p];
                y2 = h2[p] * cc2[p] + y2;
                ee = ee * E2;
            }
            xp[(size_t)tl * DIQ] = f2bf(fmaf(xt, Dd, y2.x + y2.y));
            xt = xnext;
        }
#pragma unroll
        for (int p = 0; p < 8; p++) { h[2 * p] = h2[p].x; h[2 * p + 1] = h2[p].y; }
    } else {
        for (int tl = 0; tl < CT; tl++) {
            float xnext = (tl + 1 < CT) ? bf2f(xp[(size_t)(tl + 1) * DIQ]) : 0.f;
            const float4* s4 = sd4 + tl * 12;
            float qq[16], bb[16], cc[16];
            *(float4*)&qq[0] = s4[0]; *(float4*)&qq[4] = s4[1];
            *(float4*)&qq[8] = s4[2]; *(float4*)&qq[12] = s4[3];
            *(float4*)&bb[0] = s4[4]; *(float4*)&bb[4] = s4[5];
            *(float4*)&bb[8] = s4[6]; *(float4*)&bb[12] = s4[7];
            *(float4*)&cc[0] = s4[8]; *(float4*)&cc[4] = s4[9];
            *(float4*)&cc[8] = s4[10]; *(float4*)&cc[12] = s4[11];
            float draw = dtb;
#pragma unroll
            for (int rr = 0; rr < 16; rr++) draw = fmaf(qq[rr], dtw[rr], draw);
            float dt = softplusf(draw);
            S += dt;
            float dtx = dt * xt;
            float y = 0.f;
#pragma unroll
            for (int n = 0; n < 16; n++) {
                float e = __expf(dt * Ad[n]);
                h[n] = fmaf(h[n], e, dtx * bb[n]);
                y = fmaf(h[n], cc[n], y);
            }
            xp[(size_t)tl * DIQ] = f2bf(fmaf(xt, Dd, y));
            xt = xnext;
        }
    }
    size_t hb = ((size_t)(seq * CCH + c) * 16) * DIQ + ch;
#pragma unroll
    for (int n = 0; n < 16; n++) hbuf[hb + (size_t)n * DIQ] = h[n];
    sbuf[(size_t)(seq * CCH + c) * DIQ + ch] = S;
}

__global__ __launch_bounds__(512) void k_scan2(const float* __restrict__ A_log,
                                               float* __restrict__ hbuf,
                                               const float* __restrict__ sbuf) {
    int seq = blockIdx.x;
    int inst = seq >> 3;
    int ch = threadIdx.x;
    int wo = inst * DIQ + ch;
    float Ad[16];
#pragma unroll
    for (int n = 0; n < 16; n++) Ad[n] = -__expf(A_log[(size_t)wo * 16 + n]);
    float hin[16];
#pragma unroll
    for (int n = 0; n < 16; n++) hin[n] = 0.f;
    for (int c = 0; c < CCH; c++) {
        size_t hb = ((size_t)(seq * CCH + c) * 16) * DIQ + ch;
        float Sc = sbuf[(size_t)(seq * CCH + c) * DIQ + ch];
        float he[16];
#pragma unroll
        for (int n = 0; n < 16; n++) he[n] = hbuf[hb + (size_t)n * DIQ];
#pragma unroll
        for (int n = 0; n < 16; n++) hbuf[hb + (size_t)n * DIQ] = hin[n];
#pragma unroll
        for (int n = 0; n < 16; n++) hin[n] = fmaf(hin[n], __expf(Ad[n] * Sc), he[n]);
    }
}

// pass 3: stages only dt-rows (cols 0..3) + C-rows (cols 8..11): 16KB LDS
__global__ __launch_bounds__(256) void k_scan3(ushortT* __restrict__ scanX,
                                               const float* __restrict__ xdbl,
                                               const float* __restrict__ dt_w,
                                               const float* __restrict__ dt_b,
                                               const float* __restrict__ A_log,
                                               const float* __restrict__ hbuf) {
    int bid = blockIdx.x;
    int seq = bid / (2 * (CCH - 1));
    int r = bid % (2 * (CCH - 1));
    int c = 1 + (r >> 1), half = r & 1;
    int inst = seq >> 3;
    int ch = half * 256 + threadIdx.x;

    const float4* xd4 = (const float4*)(xdbl + ((size_t)seq * LQ + c * CT) * 48);
    ushortT* xp = scanX + ((size_t)seq * LQ + c * CT) * DIQ + ch;
    int wo = inst * DIQ + ch;
    float dtw[16], Ad[16];
#pragma unroll
    for (int rr = 0; rr < 16; rr++) dtw[rr] = dt_w[(size_t)wo * 16 + rr];
    float dtb = dt_b[wo];
    float amax = -1e30f;
    bool fastA = true;
#pragma unroll
    for (int n = 0; n < 16; n++) {
        Ad[n] = -__expf(A_log[(size_t)wo * 16 + n]);
        amax = fmaxf(amax, Ad[n]);
        fastA = fastA && (fabsf(Ad[n] + (float)(n + 1)) < 1e-3f * (n + 1));
    }
    float hin[16];
    size_t hb = ((size_t)(seq * CCH + c) * 16) * DIQ + ch;
#pragma unroll
    for (int n = 0; n < 16; n++) hin[n] = hbuf[hb + (size_t)n * DIQ];

    __shared__ float4 sd4[CT * 8];  // 16KB: q (0..3) + cc (4..7)
    for (int u = threadIdx.x; u < CT * 8; u += 256) {
        int t = u >> 3, q = u & 7;
        sd4[u] = xd4[t * 12 + (q < 4 ? q : q + 4)];
    }
    __syncthreads();

    if (fastA) {
        __attribute__((aligned(16))) f32x2 dtw2[8], hin2[8];
#pragma unroll
        for (int p = 0; p < 8; p++) {
            dtw2[p] = (f32x2){dtw[2 * p], dtw[2 * p + 1]};
            hin2[p] = (f32x2){hin[2 * p], hin[2 * p + 1]};
        }
        float S = 0.f;
        for (int tl = 0; tl < CT; tl++) {
            const float4* s4 = sd4 + tl * 8;
            __attribute__((aligned(16))) f32x2 qq2[8], cc2[8];
            *(float4*)&qq2[0] = s4[0]; *(float4*)&qq2[2] = s4[1];
            *(float4*)&qq2[4] = s4[2]; *(float4*)&qq2[6] = s4[3];
            f32x2 dacc = (f32x2){dtb, 0.f};
#pragma unroll
            for (int p = 0; p < 8; p++) dacc = qq2[p] * dtw2[p] + dacc;
            S += softplusf(dacc.x + dacc.y);
            if (__all(-S < -30.f)) break;  // amax ≈ -1 in fastA
            *(float4*)&cc2[0] = s4[4]; *(float4*)&cc2[2] = s4[5];
            *(float4*)&cc2[4] = s4[6]; *(float4*)&cc2[6] = s4[7];
            float eS = __expf(-S);
            float E = eS * eS;
            f32x2 ee = (f32x2){eS, E};
            f32x2 E2 = (f32x2){E, E};
            f32x2 corr2 = (f32x2){0.f, 0.f};
#pragma unroll
            for (int p = 0; p < 8; p++) {
                corr2 = (ee * hin2[p]) * cc2[p] + corr2;
                ee = ee * E2;
            }
            xp[(size_t)tl * DIQ] = f2bf(bf2f(xp[(size_t)tl * DIQ]) + corr2.x + corr2.y);
        }
    } else {
        float S = 0.f;
        for (int tl = 0; tl < CT; tl++) {
            const float4* s4 = sd4 + tl * 8;
            float qq[16], cc[16];
            *(float4*)&qq[0] = s4[0]; *(float4*)&qq[4] = s4[1];
            *(float4*)&qq[8] = s4[2]; *(float4*)&qq[12] = s4[3];
            float draw = dtb;
#pragma unroll
            for (int rr = 0; rr < 16; rr++) draw = fmaf(qq[rr], dtw[rr], draw);
            S += softplusf(draw);
            if (__all(amax * S < -30.f)) break;
            *(float4*)&cc[0] = s4[4]; *(float4*)&cc[4] = s4[5];
            *(float4*)&cc[8] = s4[6]; *(float4*)&cc[12] = s4[7];
            float corr = 0.f;
#pragma unroll
            for (int n = 0; n < 16; n++)
                corr = fmaf(__expf(Ad[n] * S) * hin[n], cc[n], corr);
            xp[(size_t)tl * DIQ] = f2bf(bf2f(xp[(size_t)tl * DIQ]) + corr);
        }
    }
}

// ---------------- stage-1 mean/max over L (moutb bf16 input) ----------------
__global__ void k_redu1(const ushortT* __restrict__ mo, float* __restrict__ psum,
                        float* __restrict__ pmax) {
    int b = blockIdx.x >> 5, tc = blockIdx.x & 31;  // 192 threads
    int ch0 = threadIdx.x * 4;
    const ushortT* p = mo + ((size_t)b * LQ + tc * 32) * DMQ + ch0;
    float s[4] = {0.f, 0.f, 0.f, 0.f};
    float m[4] = {-3.4e38f, -3.4e38f, -3.4e38f, -3.4e38f};
    for (int t = 0; t < 32; t++) {
        ushort4 v = *(const ushort4*)(p + (size_t)t * DMQ);
        float f0 = bf2f(v.x), f1 = bf2f(v.y), f2 = bf2f(v.z), f3 = bf2f(v.w);
        s[0] += f0; s[1] += f1; s[2] += f2; s[3] += f3;
        m[0] = fmaxf(m[0], f0); m[1] = fmaxf(m[1], f1);
        m[2] = fmaxf(m[2], f2); m[3] = fmaxf(m[3], f3);
    }
    *(float4*)(psum + (size_t)(b * 32 + tc) * DMQ + ch0) = *(float4*)s;
    *(float4*)(pmax + (size_t)(b * 32 + tc) * DMQ + ch0) = *(float4*)m;
}

__global__ void k_redu2(const float* __restrict__ psum, const float* __restrict__ pmax,
                        float* __restrict__ avg, float* __restrict__ mx) {
    int idx = blockIdx.x * 256 + threadIdx.x;  // 0..6143
    int b = idx / DMQ, ch = idx % DMQ;
    float s = 0.f, m = -3.4e38f;
    for (int tc = 0; tc < 32; tc++) {
        s += psum[(size_t)(b * 32 + tc) * DMQ + ch];
        m = fmaxf(m, pmax[(size_t)(b * 32 + tc) * DMQ + ch]);
    }
    avg[idx] = s * (1.f / LQ);
    mx[idx] = m;
}

// ---- hs[b][j]: wave-per-output GEMV ----
__global__ __launch_bounds__(256) void k_att1(const float* __restrict__ avg,
                                              const float* __restrict__ mx,
                                              const float* __restrict__ w1,
                                              float* __restrict__ hs) {
    int gw = (blockIdx.x * 256 + threadIdx.x) >> 6;  // 0..3071
    int lane = threadIdx.x & 63;
    int b = gw / 384, j = gw % 384;
    const float* w = w1 + (size_t)j * DMQ;
    const float* a = avg + (size_t)b * DMQ;
    const float* m2 = mx + (size_t)b * DMQ;
    float s1 = 0.f, s2 = 0.f;
#pragma unroll
    for (int it = 0; it < 3; it++) {
        int k = it * 256 + lane * 4;
        float4 wv = *(const float4*)(w + k);
        float4 av = *(const float4*)(a + k);
        float4 mv = *(const float4*)(m2 + k);
        s1 = fmaf(av.x, wv.x, s1); s1 = fmaf(av.y, wv.y, s1);
        s1 = fmaf(av.z, wv.z, s1); s1 = fmaf(av.w, wv.w, s1);
        s2 = fmaf(mv.x, wv.x, s2); s2 = fmaf(mv.y, wv.y, s2);
        s2 = fmaf(mv.z, wv.z, s2); s2 = fmaf(mv.w, wv.w, s2);
    }
#pragma unroll
    for (int o = 32; o > 0; o >>= 1) {
        s1 += __shfl_xor(s1, o);
        s2 += __shfl_xor(s2, o);
    }
    if (lane == 0) hs[gw] = fmaxf(s1, 0.f) + fmaxf(s2, 0.f);
}

// ---- att[b][n]: wave-per-output GEMV ----
__global__ __launch_bounds__(256) void k_att2(const float* __restrict__ hs,
                                              const float* __restrict__ w2,
                                              float* __restrict__ att) {
    int gw = (blockIdx.x * 256 + threadIdx.x) >> 6;  // 0..6143
    int lane = threadIdx.x & 63;
    int b = gw / DMQ, n = gw % DMQ;
    const float* w = w2 + (size_t)n * 384;
    const float* h = hs + (size_t)b * 384;
    float s = 0.f;
#pragma unroll
    for (int it = 0; it < 3; it++) {
        int k = it * 128 + lane * 2;
        float2 wv = *(const float2*)(w + k);
        float2 hv = *(const float2*)(h + k);
        s = fmaf(hv.x, wv.x, s);
        s = fmaf(hv.y, wv.y, s);
    }
#pragma unroll
    for (int o = 32; o > 0; o >>= 1) s += __shfl_xor(s, o);
    if (lane == 0) att[gw] = sigf(s);
}

__global__ void k_diag(float* __restrict__ o, float v) {
    if (blockIdx.x == 0 && threadIdx.x == 0) o[0] = v;
}

extern "C" void kernel_launch(void* const* d_in, const int* in_sizes, int n_in, void* d_out,
                              int out_size, void* d_ws, size_t ws_size, hipStream_t stream) {
    (void)in_sizes; (void)n_in; (void)out_size;
    const float* hid = (const float*)d_in[0];
    const int* mask = (const int*)d_in[1];
    const float* pool_w = (const float*)d_in[2];
    const float* pool_b = (const float*)d_in[3];
    const float* bn_g = (const float*)d_in[4];
    const float* bn_b = (const float*)d_in[5];
    const float* bn_rm = (const float*)d_in[6];
    const float* bn_rv = (const float*)d_in[7];
    const float* ipw = (const float*)d_in[8];
    const float* cw = (const float*)d_in[9];
    const float* cb = (const float*)d_in[10];
    const float* xpw = (const float*)d_in[11];
    const float* dtw = (const float*)d_in[12];
    const float* dtb = (const float*)d_in[13];
    const float* alog = (const float*)d_in[14];
    const float* Dpp = (const float*)d_in[15];
    const float* mow = (const float*)d_in[16];
    const float* opw = (const float*)d_in[17];
    const float* opb = (const float*)d_in[18];
    const float* caw1 = (const float*)d_in[19];
    const float* caw2 = (const float*)d_in[20];
    const float* fusw = (const float*)d_in[21];
    const float* fusb = (const float*)d_in[22];
    float* out = (float*)d_out;

    // workspace layout (float-equivalent offsets)
    const size_t O_IPWB = 32768;
    const size_t O_XPWB = 819200;
    const size_t O_FUSWB = 1015808;
    const size_t O_WTMPB = 1310720;
    const size_t O_XDBL = 1703936;
    const size_t O_CBASE = 4063232;   // cbase bf16 / later moutb bf16
    const size_t O_RAWX = 7208960;    // rawx / hbuf+sbuf / gbuf
    const size_t O_SCANX = 19791872;  // scanX bf16 / later psum+pmax+fuswb8
    const size_t TOTAL_F = 32374784;  // 129.5 MB
    if (ws_size < TOTAL_F * 4) {
        k_diag<<<1, 64, 0, stream>>>(out, (float)(ws_size >> 20));
        return;
    }

    float* ws = (float*)d_ws;
    int* lengths = (int*)ws;
    float* att = ws + 1024;
    float* avg = att + 6144;
    float* mxp = avg + 6144;
    float* hs = mxp + 6144;
    ushortT* ipwb = (ushortT*)(ws + O_IPWB);
    ushortT* xpwb = (ushortT*)(ws + O_XPWB);
    ushortT* fuswb = (ushortT*)(ws + O_FUSWB);
    ushortT* wtmpb = (ushortT*)(ws + O_WTMPB);
    float* xdbl = ws + O_XDBL;
    ushortT* cbase = (ushortT*)(ws + O_CBASE);
    ushortT* rawx = (ushortT*)(ws + O_RAWX);
    ushortT* scanX = (ushortT*)(ws + O_SCANX);
    // overlays
    float* hbuf = ws + O_RAWX;            // rawx dead after dwconv
    float* sbuf = hbuf + 3145728;
    ushortT* gbuf = rawx;                 // hbuf/sbuf dead after scan3
    ushortT* moutb = cbase;               // cbase dead after z-GEMM
    float* psum = ws + O_SCANX;           // scanX dead after z-GEMM
    float* pmax = psum + 196608;
    ushortT* fuswb8 = (ushortT*)(pmax + 196608);  // fits in scanX region

    // ---- prep ----
    k_lengths<<<dim3(8), dim3(256), 0, stream>>>(mask, lengths);
    k_prep<<<dim3(9984), dim3(256), 0, stream>>>(ipw, fusw, xpw, ipwb, fuswb, xpwb);
    k_wfuse<<<dim3(768), dim3(256), 0, stream>>>(opw, mow, wtmpb);

    // ---- pool (all scales) ----
    k_pool<<<dim3(3 * 8192), dim3(64), 0, stream>>>(hid, pool_w, pool_b, bn_g, bn_b, bn_rm,
                                                    bn_rv, cbase);

    // ---- in_proj x-half (all 6 insts), flip odd insts ----
    gemm_bf16<2, 0, 0, 0, 1, 0><<<dim3(4, 64, 6), 256, 0, stream>>>(
        cbase, ipwb, rawx, nullptr, nullptr, lengths, 512, 256, 256, 512, 0, 2097152, 1,
        262144, 4194304, 0, 0, 0, 0);

    // ---- dwconv + SiLU ----
    k_dwconv<<<dim3(384), dim3(256), 0, stream>>>(rawx, cw, cb, scanX);

    // ---- x_proj ----
    gemm_bf16<0, 0, 0, 0, 0, 0><<<dim3(1, 64, 6), 256, 0, stream>>>(
        scanX, xpwb, xdbl, nullptr, nullptr, lengths, 48, 512, 512, 48, 0, 4194304, 0, 65536,
        393216, 0, 0, 0, 0);

    // ---- chunked selective scan (in place on scanX) ----
    k_scan1<<<dim3(48 * CCH * 2), dim3(256), 0, stream>>>(scanX, xdbl, dtw, dtb, alog, Dpp,
                                                          hbuf, sbuf);
    k_scan2<<<dim3(48), dim3(512), 0, stream>>>(alog, hbuf, sbuf);
    k_scan3<<<dim3(48 * (CCH - 1) * 2), dim3(256), 0, stream>>>(scanX, xdbl, dtw, dtb, alog,
                                                                hbuf);

    // ---- in_proj z-half + gate epilogue -> gbuf (dir-interleaved, unflip-scatter) ----
    gemm_bf16<2, 2, 0, 0, 1, 1><<<dim3(4, 64, 6), 256, 0, stream>>>(
        cbase, ipwb + 131072, gbuf, nullptr, scanX, lengths, 512, 256, 256, 1024, 512,
        2097152, 1, 262144, 8388608, 512, 1, 4194304, 0);

    // ---- single fused mo+op GEMM (K=1024) -> moutb bf16 (+bias) ----
    gemm_bf16<0, 0, 1, 0, 1, 0><<<dim3(2, 64, 3), 256, 0, stream>>>(
        gbuf, wtmpb, moutb, opb, nullptr, lengths, 256, 1024, 1024, 768, 0, 8388608, 0,
        262144, 256, 0, 0, 0, 256);

    // ---- attention pooling -> per-batch scaled fus weight -> final projection ----
    k_redu1<<<dim3(256), dim3(192), 0, stream>>>(moutb, psum, pmax);
    k_redu2<<<dim3(24), dim3(256), 0, stream>>>(psum, pmax, avg, mxp);
    k_att1<<<dim3(768), dim3(256), 0, stream>>>(avg, mxp, caw1, hs);
    k_att2<<<dim3(1536), dim3(256), 0, stream>>>(hs, caw2, att);
    k_fusw8<<<dim3(4608), dim3(256), 0, stream>>>(fusw, att, fuswb8);
    gemm_bf16<0, 0, 1, 0, 0, 0><<<dim3(6, 8, 8), 256, 0, stream>>>(
        moutb, fuswb8, out, fusb, nullptr, lengths, DMQ, DMQ, DMQ, DMQ, 0, 786432, 0, 589824,
        786432, 0, 0, 0, 0);
}

// Round 19
// 367.148 us; speedup vs baseline: 1.0612x; 1.0052x over previous
//
#include <hip/hip_runtime.h>
#include <cstddef>
#include <cstdint>

#define LQ 1024
#define DMQ 768
#define DSQ 256
#define DIQ 512
#define CCH 8
#define CT (LQ / CCH)

typedef unsigned short ushortT;
using f32x4 = __attribute__((ext_vector_type(4))) float;
using f32x2 = __attribute__((ext_vector_type(2))) float;
using bf16x8 = __attribute__((ext_vector_type(8))) short;
using u16x8 = __attribute__((ext_vector_type(8))) unsigned short;

__device__ __forceinline__ float sigf(float x) { return 1.f / (1.f + __expf(-x)); }
__device__ __forceinline__ float softplusf(float x) {
    return fmaxf(x, 0.f) + __logf(1.f + __expf(-fabsf(x)));
}
__device__ __forceinline__ ushortT f2bf(float f) {
    unsigned u = __float_as_uint(f);
    u += 0x7FFFu + ((u >> 16) & 1u);
    return (ushortT)(u >> 16);
}
__device__ __forceinline__ float bf2f(ushortT u) {
    return __uint_as_float(((unsigned)u) << 16);
}
__device__ __forceinline__ void gload_lds16(const void* g, void* l) {
    __builtin_amdgcn_global_load_lds((const __attribute__((address_space(1))) void*)g,
                                     (__attribute__((address_space(3))) void*)l, 16, 0, 0);
}

// ---------------- lengths ----------------
__global__ void k_lengths(const int* __restrict__ mask, int* __restrict__ lengths) {
    int b = blockIdx.x;
    int s = 0;
    for (int t = threadIdx.x; t < LQ; t += 256) s += mask[b * LQ + t];
    __shared__ int sm[256];
    sm[threadIdx.x] = s;
    __syncthreads();
    for (int o = 128; o > 0; o >>= 1) {
        if (threadIdx.x < o) sm[threadIdx.x] += sm[threadIdx.x + o];
        __syncthreads();
    }
    if (threadIdx.x == 0) lengths[b] = sm[0];
}

// ---------------- merged weight conversion ----------------
__global__ void k_prep(const float* __restrict__ ipw, const float* __restrict__ fusw,
                       const float* __restrict__ xpw, ushortT* __restrict__ ipwb,
                       ushortT* __restrict__ fuswb, ushortT* __restrict__ xpwb) {
    int i = blockIdx.x * 256 + threadIdx.x;
    if (i < 1572864) { ipwb[i] = f2bf(ipw[i]); return; }
    i -= 1572864;
    if (i < 589824) { fuswb[i] = f2bf(fusw[i]); return; }
    i -= 589824;
    if (i >= 393216) return;
    int inst = i >> 16, rem = i & 65535;
    int row = rem >> 9, col = rem & 511;
    float v = (row < 48) ? xpw[((size_t)inst * 48 + row) * 512 + col] : 0.f;
    xpwb[i] = f2bf(v);
}

// -------- fused weight, dir-interleaved: wf2[i][m][dir*512+d] --------
__global__ void k_wfuse(const float* __restrict__ opw, const float* __restrict__ mow,
                        ushortT* __restrict__ wf) {
    int idx = blockIdx.x * 256 + threadIdx.x;  // 196608 = 6*256*128
    int inst = idx >> 15;
    int rem = idx & 32767;
    int m = rem >> 7;
    int d0 = (rem & 127) * 4;
    int i = inst >> 1, dir = inst & 1;
    const float* a = opw + (size_t)i * 131072 + dir * 256 + (size_t)m * 512;
    const float* bm = mow + (size_t)inst * 131072 + d0;
    float s0 = 0.f, s1 = 0.f, s2 = 0.f, s3 = 0.f;
    for (int c = 0; c < 256; c++) {
        float av = a[c];
        float4 bv = *(const float4*)(bm + (size_t)c * 512);
        s0 = fmaf(av, bv.x, s0);
        s1 = fmaf(av, bv.y, s1);
        s2 = fmaf(av, bv.z, s2);
        s3 = fmaf(av, bv.w, s3);
    }
    ushort4 r = {f2bf(s0), f2bf(s1), f2bf(s2), f2bf(s3)};
    *(ushort4*)(wf + ((size_t)i * 256 + m) * 1024 + dir * 512 + d0) = r;
}

// -------- per-batch att-scaled fus weight --------
__global__ void k_fusw8(const float* __restrict__ fusw, const float* __restrict__ att,
                        ushortT* __restrict__ wf8) {
    int idx = blockIdx.x * 256 + threadIdx.x;  // 8*768*192
    int b = idx / 147456;
    int rem = idx % 147456;
    int n = rem / 192;
    int k0 = (rem % 192) * 4;
    float4 w = *(const float4*)(fusw + (size_t)n * 768 + k0);
    float4 a = *(const float4*)(att + (size_t)b * 768 + k0);
    ushort4 r = {f2bf(w.x * a.x), f2bf(w.y * a.y), f2bf(w.z * a.z), f2bf(w.w * a.w)};
    *(ushort4*)(wf8 + ((size_t)(b * 768 + n)) * 768 + k0) = r;
}

// ------- dilated dw conv + BN + GELU -> c bf16 (all 3 scales, float4/thread) -------
__global__ __launch_bounds__(64) void k_pool(const float* __restrict__ hid,
                                             const float* __restrict__ pw,
                                             const float* __restrict__ pb,
                                             const float* __restrict__ bg,
                                             const float* __restrict__ bb,
                                             const float* __restrict__ brm,
                                             const float* __restrict__ brv,
                                             ushortT* __restrict__ cdst) {
    int gidx = blockIdx.x;  // 3*8192
    int isc = gidx >> 13;
    int idx = gidx & 8191;
    int l = idx & (LQ - 1);
    int b = idx >> 10;
    int ch0 = threadIdx.x * 4;
    int dil = 1 << isc;
    int wci0 = isc * DSQ + ch0;
    const float* xb = hid + (size_t)b * LQ * DMQ + isc * DSQ + ch0;
    float wv[12];
    *(float4*)&wv[0] = *(const float4*)(pw + (size_t)wci0 * 3);
    *(float4*)&wv[4] = *(const float4*)(pw + (size_t)wci0 * 3 + 4);
    *(float4*)&wv[8] = *(const float4*)(pw + (size_t)wci0 * 3 + 8);
    float pbv[4], bgv[4], bbv[4], rmv[4], rvv[4];
    *(float4*)pbv = *(const float4*)(pb + wci0);
    *(float4*)bgv = *(const float4*)(bg + wci0);
    *(float4*)bbv = *(const float4*)(bb + wci0);
    *(float4*)rmv = *(const float4*)(brm + wci0);
    *(float4*)rvv = *(const float4*)(brv + wci0);
    float xm[4] = {0.f, 0.f, 0.f, 0.f}, xc[4], xp[4] = {0.f, 0.f, 0.f, 0.f};
    int lm = l - dil, lp = l + dil;
    if (lm >= 0) *(float4*)xm = *(const float4*)(xb + (size_t)lm * DMQ);
    *(float4*)xc = *(const float4*)(xb + (size_t)l * DMQ);
    if (lp < LQ) *(float4*)xp = *(const float4*)(xb + (size_t)lp * DMQ);
    ushort4 o;
#pragma unroll
    for (int j = 0; j < 4; j++) {
        float acc = pbv[j];
        acc = fmaf(wv[j * 3 + 0], xm[j], acc);
        acc = fmaf(wv[j * 3 + 1], xc[j], acc);
        acc = fmaf(wv[j * 3 + 2], xp[j], acc);
        float xn = (acc - rmv[j]) * rsqrtf(rvv[j] + 1e-5f) * bgv[j] + bbv[j];
        float y = 0.5f * xn * (1.0f + erff(xn * 0.70710678118654752f));
        ((ushortT*)&o)[j] = f2bf(y);
    }
    *(ushort4*)(cdst + (size_t)isc * 2097152 + (size_t)idx * DSQ + ch0) = o;
}

// ---------------- batched bf16 GEMM: dbuf pipeline + f32-staged coalesced epilogue ----
template <int FLIPA, int FLIPC, int BIAS, int ACC, int CBF16, int GATE>
__global__ __launch_bounds__(256) void gemm_bf16(
    const ushortT* __restrict__ A, const ushortT* __restrict__ Bw, void* __restrict__ Cv,
    const float* __restrict__ bias, const ushortT* __restrict__ Yb,
    const int* __restrict__ lengths, int N, int Kd, int lda, int ldc, int ldy, long sAz,
    int zshiftA, long sBz, long sCz, long sCzOdd, int zshiftC, long sYz, int sBiasz) {
    __shared__ ushortT Als[2][8192];
    __shared__ ushortT Bls[2][8192];
    const int z = blockIdx.z;
    A += (size_t)(z >> zshiftA) * sAz;
    Bw += (size_t)z * sBz;
    size_t cbase = (size_t)(z >> zshiftC) * sCz +
                   (size_t)(z & ((1 << zshiftC) - 1)) * sCzOdd;
    float* Cf = (float*)Cv + (CBF16 ? 0 : cbase);
    ushortT* Cb = (ushortT*)Cv + (CBF16 ? cbase : 0);
    if (BIAS) bias += (size_t)z * sBiasz;
    if (GATE) Yb += (size_t)z * sYz;

    const int tid = threadIdx.x;
    const int lane = tid & 63;
    const int wave = tid >> 6;
    const int wr = wave >> 1, wc = wave & 1;
    const int row0 = blockIdx.y * 128, col0 = blockIdx.x * 128;
    const bool doflipA = (FLIPA == 1) || (FLIPA == 2 && (z & 1));
    const bool doflipC = (FLIPC == 1) || (FLIPC == 2 && (z & 1));
    int len = 0;
    if (FLIPA || FLIPC) len = lengths[row0 >> 10];

    const int srow = wave * 8 + (lane >> 3);  // + it*32
    const int scol = (lane & 7) * 8;

    auto stage = [&](int buf, int k0) {
#pragma unroll
        for (int it = 0; it < 4; it++) {
            int row = it * 32 + srow;
            int grow = row0 + row;
            if (FLIPA) {
                if (doflipA) {
                    int t = grow & (LQ - 1);
                    int ts = (t < len) ? (len - 1 - t) : t;
                    grow = (grow & ~(LQ - 1)) | ts;
                }
            }
            gload_lds16(A + (size_t)grow * lda + k0 + scol,
                        &Als[buf][it * 2048 + wave * 512]);
        }
#pragma unroll
        for (int it = 0; it < 4; it++) {
            int row = it * 32 + srow;
            gload_lds16(Bw + (size_t)(col0 + row) * Kd + k0 + scol,
                        &Bls[buf][it * 2048 + wave * 512]);
        }
    };

    f32x4 acc[4][4];
#pragma unroll
    for (int i = 0; i < 4; i++)
#pragma unroll
        for (int j = 0; j < 4; j++) acc[i][j] = (f32x4){0.f, 0.f, 0.f, 0.f};

    const int niter = Kd >> 6;
    stage(0, 0);
    for (int it = 0; it < niter; ++it) {
        const int cur = it & 1;
        if (it + 1 < niter) {
            stage(cur ^ 1, (it + 1) << 6);
            asm volatile("s_waitcnt vmcnt(8)" ::: "memory");
        } else {
            asm volatile("s_waitcnt vmcnt(0)" ::: "memory");
        }
        __builtin_amdgcn_sched_barrier(0);
        __builtin_amdgcn_s_barrier();
        const ushortT* Ab = Als[cur];
        const ushortT* Bb = Bls[cur];
#pragma unroll
        for (int ks = 0; ks < 2; ks++) {
            bf16x8 am[4], bv[4];
#pragma unroll
            for (int f = 0; f < 4; f++) {
                am[f] = *(const bf16x8*)&Ab[(wr * 64 + f * 16 + (lane & 15)) * 64 + ks * 32 +
                                            (lane >> 4) * 8];
                bv[f] = *(const bf16x8*)&Bb[(wc * 64 + f * 16 + (lane & 15)) * 64 + ks * 32 +
                                            (lane >> 4) * 8];
            }
#pragma unroll
            for (int fm = 0; fm < 4; fm++)
#pragma unroll
                for (int fn = 0; fn < 4; fn++)
                    acc[fm][fn] = __builtin_amdgcn_mfma_f32_16x16x32_bf16(am[fm], bv[fn],
                                                                          acc[fm][fn], 0, 0, 0);
        }
        asm volatile("" ::: "memory");
        __builtin_amdgcn_s_barrier();
    }

    if (CBF16) {
        // f32-staged epilogue: 4 phases of 32 rows; coalesced GATE/BIAS at store time.
        float* Cs = (float*)Als;                // 32 x 132 f32 staging (16.9 KB)
        const int sr = tid >> 4;                // 0..15 store row
        const int sc8 = (tid & 15) * 8;         // store col group (x8)
#pragma unroll
        for (int ph = 0; ph < 4; ph++) {
            __syncthreads();
            if (wr == (ph >> 1)) {
#pragma unroll
                for (int f2 = 0; f2 < 2; f2++) {
                    int fm = (ph & 1) * 2 + f2;
#pragma unroll
                    for (int r = 0; r < 4; r++) {
                        int slot = f2 * 16 + (lane >> 4) * 4 + r;
#pragma unroll
                        for (int fn = 0; fn < 4; fn++) {
                            int col = wc * 64 + fn * 16 + (lane & 15);
                            Cs[slot * 132 + col] = acc[fm][fn][r];
                        }
                    }
                }
            }
            __syncthreads();
#pragma unroll
            for (int it = 0; it < 2; it++) {
                int s = it * 16 + sr;
                int rowt = ph * 32 + s;
                int growY = row0 + rowt;
                int growC = growY;
                if (FLIPC) {
                    if (doflipC) {
                        int t = growC & (LQ - 1);
                        int ts = (t < len) ? (len - 1 - t) : t;
                        growC = (growC & ~(LQ - 1)) | ts;
                    }
                }
                float vv[8];
                *(float4*)&vv[0] = *(const float4*)&Cs[s * 132 + sc8];
                *(float4*)&vv[4] = *(const float4*)&Cs[s * 132 + sc8 + 4];
                if (GATE) {
                    u16x8 yv = *(const u16x8*)(Yb + (size_t)growY * ldy + col0 + sc8);
#pragma unroll
                    for (int j = 0; j < 8; j++) {
                        float g = vv[j];
                        vv[j] = bf2f(yv[j]) * g * sigf(g);
                    }
                }
                if (BIAS) {
                    float4 b0 = *(const float4*)(bias + col0 + sc8);
                    float4 b1 = *(const float4*)(bias + col0 + sc8 + 4);
                    vv[0] += b0.x; vv[1] += b0.y; vv[2] += b0.z; vv[3] += b0.w;
                    vv[4] += b1.x; vv[5] += b1.y; vv[6] += b1.z; vv[7] += b1.w;
                }
                u16x8 o;
#pragma unroll
                for (int j = 0; j < 8; j++) o[j] = f2bf(vv[j]);
                *(u16x8*)(Cb + (size_t)growC * ldc + col0 + sc8) = o;
            }
        }
    } else {
#pragma unroll
        for (int fm = 0; fm < 4; fm++) {
#pragma unroll
            for (int r = 0; r < 4; r++) {
                int growY = row0 + wr * 64 + fm * 16 + (lane >> 4) * 4 + r;
                int growC = growY;
                if (FLIPC) {
                    if (doflipC) {
                        int t = growC & (LQ - 1);
                        int ts = (t < len) ? (len - 1 - t) : t;
                        growC = (growC & ~(LQ - 1)) | ts;
                    }
                }
#pragma unroll
                for (int fn = 0; fn < 4; fn++) {
                    int col = col0 + wc * 64 + fn * 16 + (lane & 15);
                    if (col < N) {
                        float v = acc[fm][fn][r];
                        float* cp = Cf + (size_t)growC * ldc + col;
                        if (ACC) v += *cp;
                        if (BIAS) v += bias[col];
                        *cp = v;
                    }
                }
            }
        }
    }
}

// ---- causal dw conv (K=4) + SiLU: register-window, 8ch x 32t per thread ----
__global__ __launch_bounds__(256) void k_dwconv(const ushortT* __restrict__ rawx,
                                                const float* __restrict__ cw,
                                                const float* __restrict__ cb,
                                                ushortT* __restrict__ sx) {
    int blk = blockIdx.x;
    int tc = blk & 7;
    int sb = blk >> 3;  // inst*8+b
    int inst = sb >> 3;
    int cg = threadIdx.x & 63;
    int sub = threadIdx.x >> 6;
    int ch0 = cg * 8;
    int t0 = tc * 128 + sub * 32;
    const ushortT* base = rawx + (size_t)sb * LQ * DIQ + ch0;
    ushortT* obase = sx + (size_t)sb * LQ * DIQ + ch0;

    float w[8][4], bs[8];
#pragma unroll
    for (int j = 0; j < 8; j++) {
        float4 wv = *(const float4*)(cw + (size_t)inst * 2048 + (size_t)(ch0 + j) * 4);
        w[j][0] = wv.x; w[j][1] = wv.y; w[j][2] = wv.z; w[j][3] = wv.w;
        bs[j] = cb[inst * DIQ + ch0 + j];
    }
    float x3[8], x2[8], x1[8];
#pragma unroll
    for (int j = 0; j < 8; j++) { x3[j] = 0.f; x2[j] = 0.f; x1[j] = 0.f; }
    if (t0 >= 3) {
        u16x8 v3 = *(const u16x8*)(base + (size_t)(t0 - 3) * DIQ);
        u16x8 v2 = *(const u16x8*)(base + (size_t)(t0 - 2) * DIQ);
        u16x8 v1 = *(const u16x8*)(base + (size_t)(t0 - 1) * DIQ);
#pragma unroll
        for (int j = 0; j < 8; j++) {
            x3[j] = bf2f(v3[j]); x2[j] = bf2f(v2[j]); x1[j] = bf2f(v1[j]);
        }
    }
#pragma unroll 4
    for (int t = t0; t < t0 + 32; t++) {
        u16x8 v = *(const u16x8*)(base + (size_t)t * DIQ);
        float xc[8];
#pragma unroll
        for (int j = 0; j < 8; j++) xc[j] = bf2f(v[j]);
        u16x8 o;
#pragma unroll
        for (int j = 0; j < 8; j++) {
            float acc = bs[j];
            acc = fmaf(w[j][0], x3[j], acc);
            acc = fmaf(w[j][1], x2[j], acc);
            acc = fmaf(w[j][2], x1[j], acc);
            acc = fmaf(w[j][3], xc[j], acc);
            o[j] = f2bf(acc * sigf(acc));
        }
        *(u16x8*)(obase + (size_t)t * DIQ) = o;
#pragma unroll
        for (int j = 0; j < 8; j++) { x3[j] = x2[j]; x2[j] = x1[j]; x1[j] = xc[j]; }
    }
}

// ======== chunked selective scan (CCH=8, packed-f32 fast path) ========
__global__ __launch_bounds__(256) void k_scan1(ushortT* __restrict__ scanX,
                                               const float* __restrict__ xdbl,
                                               const float* __restrict__ dt_w,
                                               const float* __restrict__ dt_b,
                                               const float* __restrict__ A_log,
                                               const float* __restrict__ Dpp,
                                               float* __restrict__ hbuf,
                                               float* __restrict__ sbuf) {
    int bid = blockIdx.x;
    int seq = bid >> 4;
    int r = bid & 15;
    int c = r >> 1, half = r & 1;
    int inst = seq >> 3;
    int ch = half * 256 + threadIdx.x;

    const float4* xd4 = (const float4*)(xdbl + ((size_t)seq * LQ + c * CT) * 48);
    ushortT* xp = scanX + ((size_t)seq * LQ + c * CT) * DIQ + ch;
    int wo = inst * DIQ + ch;
    float dtw[16], Ad[16];
#pragma unroll
    for (int rr = 0; rr < 16; rr++) dtw[rr] = dt_w[(size_t)wo * 16 + rr];
    float dtb = dt_b[wo];
    bool fastA = true;
#pragma unroll
    for (int n = 0; n < 16; n++) {
        Ad[n] = -__expf(A_log[(size_t)wo * 16 + n]);
        fastA = fastA && (fabsf(Ad[n] + (float)(n + 1)) < 1e-3f * (n + 1));
    }
    float Dd = Dpp[wo];
    float S = 0.f;

    __shared__ float4 sd4[CT * 12];  // 24KB
    for (int u = threadIdx.x; u < CT * 12; u += 256) sd4[u] = xd4[u];
    __syncthreads();

    float h[16];
#pragma unroll
    for (int n = 0; n < 16; n++) h[n] = 0.f;

    float xt = bf2f(xp[0]);
    if (fastA) {
        __attribute__((aligned(16))) f32x2 dtw2[8], h2[8];
#pragma unroll
        for (int p = 0; p < 8; p++) {
            dtw2[p] = (f32x2){dtw[2 * p], dtw[2 * p + 1]};
            h2[p] = (f32x2){0.f, 0.f};
        }
        for (int tl = 0; tl < CT; tl++) {
            float xnext = (tl + 1 < CT) ? bf2f(xp[(size_t)(tl + 1) * DIQ]) : 0.f;
            const float4* s4 = sd4 + tl * 12;
            __attribute__((aligned(16))) f32x2 qq2[8], bb2[8], cc2[8];
            *(float4*)&qq2[0] = s4[0]; *(float4*)&qq2[2] = s4[1];
            *(float4*)&qq2[4] = s4[2]; *(float4*)&qq2[6] = s4[3];
            *(float4*)&bb2[0] = s4[4]; *(float4*)&bb2[2] = s4[5];
            *(float4*)&bb2[4] = s4[6]; *(float4*)&bb2[6] = s4[7];
            *(float4*)&cc2[0] = s4[8]; *(float4*)&cc2[2] = s4[9];
            *(float4*)&cc2[4] = s4[10]; *(float4*)&cc2[6] = s4[11];
            f32x2 dacc = (f32x2){dtb, 0.f};
#pragma unroll
            for (int p = 0; p < 8; p++) dacc = qq2[p] * dtw2[p] + dacc;
            float dt = softplusf(dacc.x + dacc.y);
            S += dt;
            float e1 = __expf(-dt);
            float E = e1 * e1;
            f32x2 ee = (f32x2){e1, E};
            f32x2 E2 = (f32x2){E, E};
            f32x2 dtx2 = (f32x2){dt * xt, dt * xt};
            f32x2 y2 = (f32x2){0.f, 0.f};
#pragma unroll
            for (int p = 0; p < 8; p++) {
                h2[p] = h2[p] * ee + dtx2 * bb2[p];
                y2 = h2[p] * cc2[p] + y2;
                ee = ee * E2;
            }
            xp[(size_t)tl * DIQ] = f2bf(fmaf(xt, Dd, y2.x + y2.y));
            xt = xnext;
        }
#pragma unroll
        for (int p = 0; p < 8; p++) { h[2 * p] = h2[p].x; h[2 * p + 1] = h2[p].y; }
    } else {
        for (int tl = 0; tl < CT; tl++) {
            float xnext = (tl + 1 < CT) ? bf2f(xp[(size_t)(tl + 1) * DIQ]) : 0.f;
            const float4* s4 = sd4 + tl * 12;
            float qq[16], bb[16], cc[16];
            *(float4*)&qq[0] = s4[0]; *(float4*)&qq[4] = s4[1];
            *(float4*)&qq[8] = s4[2]; *(float4*)&qq[12] = s4[3];
            *(float4*)&bb[0] = s4[4]; *(float4*)&bb[4] = s4[5];
            *(float4*)&bb[8] = s4[6]; *(float4*)&bb[12] = s4[7];
            *(float4*)&cc[0] = s4[8]; *(float4*)&cc[4] = s4[9];
            *(float4*)&cc[8] = s4[10]; *(float4*)&cc[12] = s4[11];
            float draw = dtb;
#pragma unroll
            for (int rr = 0; rr < 16; rr++) draw = fmaf(qq[rr], dtw[rr], draw);
            float dt = softplusf(draw);
            S += dt;
            float dtx = dt * xt;
            float y = 0.f;
#pragma unroll
            for (int n = 0; n < 16; n++) {
                float e = __expf(dt * Ad[n]);
                h[n] = fmaf(h[n], e, dtx * bb[n]);
                y = fmaf(h[n], cc[n], y);
            }
            xp[(size_t)tl * DIQ] = f2bf(fmaf(xt, Dd, y));
            xt = xnext;
        }
    }
    size_t hb = ((size_t)(seq * CCH + c) * 16) * DIQ + ch;
#pragma unroll
    for (int n = 0; n < 16; n++) hbuf[hb + (size_t)n * DIQ] = h[n];
    sbuf[(size_t)(seq * CCH + c) * DIQ + ch] = S;
}

__global__ __launch_bounds__(512) void k_scan2(const float* __restrict__ A_log,
                                               float* __restrict__ hbuf,
                                               const float* __restrict__ sbuf) {
    int seq = blockIdx.x;
    int inst = seq >> 3;
    int ch = threadIdx.x;
    int wo = inst * DIQ + ch;
    float Ad[16];
#pragma unroll
    for (int n = 0; n < 16; n++) Ad[n] = -__expf(A_log[(size_t)wo * 16 + n]);
    float hin[16];
#pragma unroll
    for (int n = 0; n < 16; n++) hin[n] = 0.f;
    for (int c = 0; c < CCH; c++) {
        size_t hb = ((size_t)(seq * CCH + c) * 16) * DIQ + ch;
        float Sc = sbuf[(size_t)(seq * CCH + c) * DIQ + ch];
        float he[16];
#pragma unroll
        for (int n = 0; n < 16; n++) he[n] = hbuf[hb + (size_t)n * DIQ];
#pragma unroll
        for (int n = 0; n < 16; n++) hbuf[hb + (size_t)n * DIQ] = hin[n];
#pragma unroll
        for (int n = 0; n < 16; n++) hin[n] = fmaf(hin[n], __expf(Ad[n] * Sc), he[n]);
    }
}

// pass 3: stages only dt-rows (cols 0..3) + C-rows (cols 8..11): 16KB LDS
__global__ __launch_bounds__(256) void k_scan3(ushortT* __restrict__ scanX,
                                               const float* __restrict__ xdbl,
                                               const float* __restrict__ dt_w,
                                               const float* __restrict__ dt_b,
                                               const float* __restrict__ A_log,
                                               const float* __restrict__ hbuf) {
    int bid = blockIdx.x;
    int seq = bid / (2 * (CCH - 1));
    int r = bid % (2 * (CCH - 1));
    int c = 1 + (r >> 1), half = r & 1;
    int inst = seq >> 3;
    int ch = half * 256 + threadIdx.x;

    const float4* xd4 = (const float4*)(xdbl + ((size_t)seq * LQ + c * CT) * 48);
    ushortT* xp = scanX + ((size_t)seq * LQ + c * CT) * DIQ + ch;
    int wo = inst * DIQ + ch;
    float dtw[16], Ad[16];
#pragma unroll
    for (int rr = 0; rr < 16; rr++) dtw[rr] = dt_w[(size_t)wo * 16 + rr];
    float dtb = dt_b[wo];
    float amax = -1e30f;
    bool fastA = true;
#pragma unroll
    for (int n = 0; n < 16; n++) {
        Ad[n] = -__expf(A_log[(size_t)wo * 16 + n]);
        amax = fmaxf(amax, Ad[n]);
        fastA = fastA && (fabsf(Ad[n] + (float)(n + 1)) < 1e-3f * (n + 1));
    }
    float hin[16];
    size_t hb = ((size_t)(seq * CCH + c) * 16) * DIQ + ch;
#pragma unroll
    for (int n = 0; n < 16; n++) hin[n] = hbuf[hb + (size_t)n * DIQ];

    __shared__ float4 sd4[CT * 8];  // 16KB: q (0..3) + cc (4..7)
    for (int u = threadIdx.x; u < CT * 8; u += 256) {
        int t = u >> 3, q = u & 7;
        sd4[u] = xd4[t * 12 + (q < 4 ? q : q + 4)];
    }
    __syncthreads();

    if (fastA) {
        __attribute__((aligned(16))) f32x2 dtw2[8], hin2[8];
#pragma unroll
        for (int p = 0; p < 8; p++) {
            dtw2[p] = (f32x2){dtw[2 * p], dtw[2 * p + 1]};
            hin2[p] = (f32x2){hin[2 * p], hin[2 * p + 1]};
        }
        float S = 0.f;
        for (int tl = 0; tl < CT; tl++) {
            const float4* s4 = sd4 + tl * 8;
            __attribute__((aligned(16))) f32x2 qq2[8], cc2[8];
            *(float4*)&qq2[0] = s4[0]; *(float4*)&qq2[2] = s4[1];
            *(float4*)&qq2[4] = s4[2]; *(float4*)&qq2[6] = s4[3];
            f32x2 dacc = (f32x2){dtb, 0.f};
#pragma unroll
            for (int p = 0; p < 8; p++) dacc = qq2[p] * dtw2[p] + dacc;
            S += softplusf(dacc.x + dacc.y);
            if (__all(-S < -30.f)) break;  // amax ≈ -1 in fastA
            *(float4*)&cc2[0] = s4[4]; *(float4*)&cc2[2] = s4[5];
            *(float4*)&cc2[4] = s4[6]; *(float4*)&cc2[6] = s4[7];
            float eS = __expf(-S);
            float E = eS * eS;
            f32x2 ee = (f32x2){eS, E};
            f32x2 E2 = (f32x2){E, E};
            f32x2 corr2 = (f32x2){0.f, 0.f};
#pragma unroll
            for (int p = 0; p < 8; p++) {
                corr2 = (ee * hin2[p]) * cc2[p] + corr2;
                ee = ee * E2;
            }
            xp[(size_t)tl * DIQ] = f2bf(bf2f(xp[(size_t)tl * DIQ]) + corr2.x + corr2.y);
        }
    } else {
        float S = 0.f;
        for (int tl = 0; tl < CT; tl++) {
            const float4* s4 = sd4 + tl * 8;
            float qq[16], cc[16];
            *(float4*)&qq[0] = s4[0]; *(float4*)&qq[4] = s4[1];
            *(float4*)&qq[8] = s4[2]; *(float4*)&qq[12] = s4[3];
            float draw = dtb;
#pragma unroll
            for (int rr = 0; rr < 16; rr++) draw = fmaf(qq[rr], dtw[rr], draw);
            S += softplusf(draw);
            if (__all(amax * S < -30.f)) break;
            *(float4*)&cc[0] = s4[4]; *(float4*)&cc[4] = s4[5];
            *(float4*)&cc[8] = s4[6]; *(float4*)&cc[12] = s4[7];
            float corr = 0.f;
#pragma unroll
            for (int n = 0; n < 16; n++)
                corr = fmaf(__expf(Ad[n] * S) * hin[n], cc[n], corr);
            xp[(size_t)tl * DIQ] = f2bf(bf2f(xp[(size_t)tl * DIQ]) + corr);
        }
    }
}

// ---------------- stage-1 mean/max over L (moutb bf16 input) ----------------
__global__ void k_redu1(const ushortT* __restrict__ mo, float* __restrict__ psum,
                        float* __restrict__ pmax) {
    int b = blockIdx.x >> 5, tc = blockIdx.x & 31;  // 192 threads
    int ch0 = threadIdx.x * 4;
    const ushortT* p = mo + ((size_t)b * LQ + tc * 32) * DMQ + ch0;
    float s[4] = {0.f, 0.f, 0.f, 0.f};
    float m[4] = {-3.4e38f, -3.4e38f, -3.4e38f, -3.4e38f};
    for (int t = 0; t < 32; t++) {
        ushort4 v = *(const ushort4*)(p + (size_t)t * DMQ);
        float f0 = bf2f(v.x), f1 = bf2f(v.y), f2 = bf2f(v.z), f3 = bf2f(v.w);
        s[0] += f0; s[1] += f1; s[2] += f2; s[3] += f3;
        m[0] = fmaxf(m[0], f0); m[1] = fmaxf(m[1], f1);
        m[2] = fmaxf(m[2], f2); m[3] = fmaxf(m[3], f3);
    }
    *(float4*)(psum + (size_t)(b * 32 + tc) * DMQ + ch0) = *(float4*)s;
    *(float4*)(pmax + (size_t)(b * 32 + tc) * DMQ + ch0) = *(float4*)m;
}

__global__ void k_redu2(const float* __restrict__ psum, const float* __restrict__ pmax,
                        float* __restrict__ avg, float* __restrict__ mx) {
    int idx = blockIdx.x * 256 + threadIdx.x;  // 0..6143
    int b = idx / DMQ, ch = idx % DMQ;
    float s = 0.f, m = -3.4e38f;
    for (int tc = 0; tc < 32; tc++) {
        s += psum[(size_t)(b * 32 + tc) * DMQ + ch];
        m = fmaxf(m, pmax[(size_t)(b * 32 + tc) * DMQ + ch]);
    }
    avg[idx] = s * (1.f / LQ);
    mx[idx] = m;
}

// ---- hs[b][j]: wave-per-output GEMV ----
__global__ __launch_bounds__(256) void k_att1(const float* __restrict__ avg,
                                              const float* __restrict__ mx,
                                              const float* __restrict__ w1,
                                              float* __restrict__ hs) {
    int gw = (blockIdx.x * 256 + threadIdx.x) >> 6;  // 0..3071
    int lane = threadIdx.x & 63;
    int b = gw / 384, j = gw % 384;
    const float* w = w1 + (size_t)j * DMQ;
    const float* a = avg + (size_t)b * DMQ;
    const float* m2 = mx + (size_t)b * DMQ;
    float s1 = 0.f, s2 = 0.f;
#pragma unroll
    for (int it = 0; it < 3; it++) {
        int k = it * 256 + lane * 4;
        float4 wv = *(const float4*)(w + k);
        float4 av = *(const float4*)(a + k);
        float4 mv = *(const float4*)(m2 + k);
        s1 = fmaf(av.x, wv.x, s1); s1 = fmaf(av.y, wv.y, s1);
        s1 = fmaf(av.z, wv.z, s1); s1 = fmaf(av.w, wv.w, s1);
        s2 = fmaf(mv.x, wv.x, s2); s2 = fmaf(mv.y, wv.y, s2);
        s2 = fmaf(mv.z, wv.z, s2); s2 = fmaf(mv.w, wv.w, s2);
    }
#pragma unroll
    for (int o = 32; o > 0; o >>= 1) {
        s1 += __shfl_xor(s1, o);
        s2 += __shfl_xor(s2, o);
    }
    if (lane == 0) hs[gw] = fmaxf(s1, 0.f) + fmaxf(s2, 0.f);
}

// ---- att[b][n]: wave-per-output GEMV ----
__global__ __launch_bounds__(256) void k_att2(const float* __restrict__ hs,
                                              const float* __restrict__ w2,
                                              float* __restrict__ att) {
    int gw = (blockIdx.x * 256 + threadIdx.x) >> 6;  // 0..6143
    int lane = threadIdx.x & 63;
    int b = gw / DMQ, n = gw % DMQ;
    const float* w = w2 + (size_t)n * 384;
    const float* h = hs + (size_t)b * 384;
    float s = 0.f;
#pragma unroll
    for (int it = 0; it < 3; it++) {
        int k = it * 128 + lane * 2;
        float2 wv = *(const float2*)(w + k);
        float2 hv = *(const float2*)(h + k);
        s = fmaf(hv.x, wv.x, s);
        s = fmaf(hv.y, wv.y, s);
    }
#pragma unroll
    for (int o = 32; o > 0; o >>= 1) s += __shfl_xor(s, o);
    if (lane == 0) att[gw] = sigf(s);
}

__global__ void k_diag(float* __restrict__ o, float v) {
    if (blockIdx.x == 0 && threadIdx.x == 0) o[0] = v;
}

extern "C" void kernel_launch(void* const* d_in, const int* in_sizes, int n_in, void* d_out,
                              int out_size, void* d_ws, size_t ws_size, hipStream_t stream) {
    (void)in_sizes; (void)n_in; (void)out_size;
    const float* hid = (const float*)d_in[0];
    const int* mask = (const int*)d_in[1];
    const float* pool_w = (const float*)d_in[2];
    const float* pool_b = (const float*)d_in[3];
    const float* bn_g = (const float*)d_in[4];
    const float* bn_b = (const float*)d_in[5];
    const float* bn_rm = (const float*)d_in[6];
    const float* bn_rv = (const float*)d_in[7];
    const float* ipw = (const float*)d_in[8];
    const float* cw = (const float*)d_in[9];
    const float* cb = (const float*)d_in[10];
    const float* xpw = (const float*)d_in[11];
    const float* dtw = (const float*)d_in[12];
    const float* dtb = (const float*)d_in[13];
    const float* alog = (const float*)d_in[14];
    const float* Dpp = (const float*)d_in[15];
    const float* mow = (const float*)d_in[16];
    const float* opw = (const float*)d_in[17];
    const float* opb = (const float*)d_in[18];
    const float* caw1 = (const float*)d_in[19];
    const float* caw2 = (const float*)d_in[20];
    const float* fusw = (const float*)d_in[21];
    const float* fusb = (const float*)d_in[22];
    float* out = (float*)d_out;

    // workspace layout (float-equivalent offsets)
    const size_t O_IPWB = 32768;
    const size_t O_XPWB = 819200;
    const size_t O_FUSWB = 1015808;
    const size_t O_WTMPB = 1310720;
    const size_t O_XDBL = 1703936;
    const size_t O_CBASE = 4063232;   // cbase bf16 / later moutb bf16
    const size_t O_RAWX = 7208960;    // rawx / hbuf+sbuf / gbuf
    const size_t O_SCANX = 19791872;  // scanX bf16 / later psum+pmax+fuswb8
    const size_t TOTAL_F = 32374784;  // 129.5 MB
    if (ws_size < TOTAL_F * 4) {
        k_diag<<<1, 64, 0, stream>>>(out, (float)(ws_size >> 20));
        return;
    }

    float* ws = (float*)d_ws;
    int* lengths = (int*)ws;
    float* att = ws + 1024;
    float* avg = att + 6144;
    float* mxp = avg + 6144;
    float* hs = mxp + 6144;
    ushortT* ipwb = (ushortT*)(ws + O_IPWB);
    ushortT* xpwb = (ushortT*)(ws + O_XPWB);
    ushortT* fuswb = (ushortT*)(ws + O_FUSWB);
    ushortT* wtmpb = (ushortT*)(ws + O_WTMPB);
    float* xdbl = ws + O_XDBL;
    ushortT* cbase = (ushortT*)(ws + O_CBASE);
    ushortT* rawx = (ushortT*)(ws + O_RAWX);
    ushortT* scanX = (ushortT*)(ws + O_SCANX);
    // overlays
    float* hbuf = ws + O_RAWX;            // rawx dead after dwconv
    float* sbuf = hbuf + 3145728;
    ushortT* gbuf = rawx;                 // hbuf/sbuf dead after scan3
    ushortT* moutb = cbase;               // cbase dead after z-GEMM
    float* psum = ws + O_SCANX;           // scanX dead after z-GEMM
    float* pmax = psum + 196608;
    ushortT* fuswb8 = (ushortT*)(pmax + 196608);  // fits in scanX region

    // ---- prep ----
    k_lengths<<<dim3(8), dim3(256), 0, stream>>>(mask, lengths);
    k_prep<<<dim3(9984), dim3(256), 0, stream>>>(ipw, fusw, xpw, ipwb, fuswb, xpwb);
    k_wfuse<<<dim3(768), dim3(256), 0, stream>>>(opw, mow, wtmpb);

    // ---- pool (all scales) ----
    k_pool<<<dim3(3 * 8192), dim3(64), 0, stream>>>(hid, pool_w, pool_b, bn_g, bn_b, bn_rm,
                                                    bn_rv, cbase);

    // ---- in_proj x-half (all 6 insts), flip odd insts ----
    gemm_bf16<2, 0, 0, 0, 1, 0><<<dim3(4, 64, 6), 256, 0, stream>>>(
        cbase, ipwb, rawx, nullptr, nullptr, lengths, 512, 256, 256, 512, 0, 2097152, 1,
        262144, 4194304, 0, 0, 0, 0);

    // ---- dwconv + SiLU ----
    k_dwconv<<<dim3(384), dim3(256), 0, stream>>>(rawx, cw, cb, scanX);

    // ---- x_proj ----
    gemm_bf16<0, 0, 0, 0, 0, 0><<<dim3(1, 64, 6), 256, 0, stream>>>(
        scanX, xpwb, xdbl, nullptr, nullptr, lengths, 48, 512, 512, 48, 0, 4194304, 0, 65536,
        393216, 0, 0, 0, 0);

    // ---- chunked selective scan (in place on scanX) ----
    k_scan1<<<dim3(48 * CCH * 2), dim3(256), 0, stream>>>(scanX, xdbl, dtw, dtb, alog, Dpp,
                                                          hbuf, sbuf);
    k_scan2<<<dim3(48), dim3(512), 0, stream>>>(alog, hbuf, sbuf);
    k_scan3<<<dim3(48 * (CCH - 1) * 2), dim3(256), 0, stream>>>(scanX, xdbl, dtw, dtb, alog,
                                                                hbuf);

    // ---- in_proj z-half + gate epilogue -> gbuf (dir-interleaved, unflip-scatter) ----
    gemm_bf16<2, 2, 0, 0, 1, 1><<<dim3(4, 64, 6), 256, 0, stream>>>(
        cbase, ipwb + 131072, gbuf, nullptr, scanX, lengths, 512, 256, 256, 1024, 512,
        2097152, 1, 262144, 8388608, 512, 1, 4194304, 0);

    // ---- single fused mo+op GEMM (K=1024) -> moutb bf16 (+bias) ----
    gemm_bf16<0, 0, 1, 0, 1, 0><<<dim3(2, 64, 3), 256, 0, stream>>>(
        gbuf, wtmpb, moutb, opb, nullptr, lengths, 256, 1024, 1024, 768, 0, 8388608, 0,
        262144, 256, 0, 0, 0, 256);

    // ---- attention pooling -> per-batch scaled fus weight -> final projection ----
    k_redu1<<<dim3(256), dim3(192), 0, stream>>>(moutb, psum, pmax);
    k_redu2<<<dim3(24), dim3(256), 0, stream>>>(psum, pmax, avg, mxp);
    k_att1<<<dim3(768), dim3(256), 0, stream>>>(avg, mxp, caw1, hs);
    k_att2<<<dim3(1536), dim3(256), 0, stream>>>(hs, caw2, att);
    k_fusw8<<<dim3(4608), dim3(256), 0, stream>>>(fusw, att, fuswb8);
    gemm_bf16<0, 0, 1, 0, 0, 0><<<dim3(6, 8, 8), 256, 0, stream>>>(
        moutb, fuswb8, out, fusb, nullptr, lengths, DMQ, DMQ, DMQ, DMQ, 0, 786432, 0, 589824,
        786432, 0, 0, 0, 0);
}